// Round 17
// baseline (293.603 us; speedup 1.0000x reference)
//
#include <hip/hip_runtime.h>
#include <hip/hip_bf16.h>
#include <math.h>

#define DD 128
#define DH 64
#define MAXN_F (1.0f - 4e-3f)
#define NTHR 512
#define NBLK 512   // 2 blocks/CU, whole grid resident

__device__ inline float wsum(float v) {
#pragma unroll
    for (int off = 32; off > 0; off >>= 1) v += __shfl_xor(v, off, 64);
    return v;
}
__device__ inline float wmax(float v) {
#pragma unroll
    for (int off = 32; off > 0; off >>= 1) v = fmaxf(v, __shfl_xor(v, off, 64));
    return v;
}
__device__ inline int wsumi(int v) {
#pragma unroll
    for (int off = 32; off > 0; off >>= 1) v += __shfl_xor(v, off, 64);
    return v;
}
__device__ inline unsigned short f2bf16(float x) {
    unsigned u = __float_as_uint(x);
    u += 0x7fffu + ((u >> 16) & 1u);   // RNE
    return (unsigned short)(u >> 16);
}
__device__ inline unsigned packbf(float a, float b) {
    return (unsigned)f2bf16(a) | ((unsigned)f2bf16(b) << 16);
}
// fast hyperbolics on HW exp2/log2 (args >= 0 here)
__device__ inline float fatanh(float z) {
    return 0.5f * __logf(__fdividef(1.f + z, 1.f - z));
}
__device__ inline float ftanh(float y) {
    y = fminf(y, 10.f);
    float e = __expf(2.f * y);
    return __fdividef(e - 1.f, e + 1.f);
}

// ---- W-in-LDS (fp32, XOR-swizzled) 4-rows-per-wave fused kernel ---------
// 512 thr = 8 waves, 2 blocks/CU. Per k4: 2 W ds_read_b128 feed 32 FMAs
// (4 rows). x rows in wave-private LDS slots, uniform-address broadcast.
__global__ __launch_bounds__(NTHR) void gemm_node_k(
    const float* __restrict__ x, const float* __restrict__ W,
    const float* __restrict__ bias,
    const float* __restrict__ atti, const float* __restrict__ attj,
    const int* __restrict__ eidx, int* __restrict__ deg,
    unsigned* __restrict__ xtb, float* __restrict__ ai, float* __restrict__ aj,
    int n, int E) {
    __shared__ float wlds[128 * 128];      // 64 KB, XOR-swizzled float4 slots
    __shared__ float2 xslot[8][4][64];     // 16 KB: per-wave 4 x rows
    const int tid = threadIdx.x;
    const int wv = tid >> 6;
    const int lane = tid & 63;
    const int l31 = lane & 31;
    const float4* W4g = reinterpret_cast<const float4*>(W);
    float4* wlds4 = reinterpret_cast<float4*>(wlds);
    // ---- stage W: logical (col c, chunk p) -> physical slot p^(c&31) ----
#pragma unroll
    for (int i = 0; i < 8; ++i) {
        int s = tid + i * NTHR;            // 0..4095
        int c = s >> 5, p = s & 31;
        wlds4[c * 32 + (p ^ (c & 31))] = W4g[s];
    }
    // ---- per-wave bias/att pipeline (registers only) ----
    float b0 = bias[lane], b1 = bias[64 + lane];
    float ai0 = atti[lane], ai1 = atti[64 + lane];
    float aj0 = attj[lane], aj1 = attj[64 + lane];
    float Sb = wsum(b0 * b0 + b1 * b1);
    float nb_ = fmaxf(sqrtf(Sb), 1e-15f);
    float th = tanhf(nb_) / nb_;
    float e0 = th * b0, e1 = th * b1;
    float Se = wsum(e0 * e0 + e1 * e1);
    float ne = fmaxf(sqrtf(Se), 1e-15f);
    if (ne > MAXN_F) { float sc = MAXN_F / ne; e0 *= sc; e1 *= sc; }
    float y2v = wsum(e0 * e0 + e1 * e1);
    float Yi0 = wsum(e0 * ai0), Yi1 = wsum(e1 * ai1);
    float Yj0 = wsum(e0 * aj0), Yj1 = wsum(e1 * aj1);
    __syncthreads();  // W staged
    // ---- row loop: 4 rows per wave per iteration ----
    const int gw = blockIdx.x * 8 + wv;
    const int nw = NBLK * 8;
    const float2* x2 = reinterpret_cast<const float2*>(x);
    const float4* wp = wlds4 + (size_t)lane * 32;   // col=lane; col=64+lane at +2048
    float2* slot = &xslot[wv][0][0];                // 4 rows x 64 float2
    const float4* sp = reinterpret_cast<const float4*>(slot);  // uniform base
    float2 pc[4];
#pragma unroll
    for (int i = 0; i < 4; ++i) {
        int r = gw * 4 + i;
        pc[i] = (r < n) ? x2[(size_t)r * 64 + lane] : make_float2(0.f, 0.f);
    }
    for (int rb = gw * 4; rb < n; rb += nw * 4) {
        // write slots + save |x|^2 partials
        float px2[4];
#pragma unroll
        for (int i = 0; i < 4; ++i) {
            slot[i * 64 + lane] = pc[i];
            px2[i] = pc[i].x * pc[i].x + pc[i].y * pc[i].y;
        }
        // prefetch next batch (in flight during k-loop)
        int rnb = rb + nw * 4;
        float2 nc[4];
#pragma unroll
        for (int i = 0; i < 4; ++i) {
            int r = rnb + i;
            nc[i] = (r < n) ? x2[(size_t)r * 64 + lane] : make_float2(0.f, 0.f);
        }
        __threadfence_block();  // slot writes visible before uniform reads
        float m[4][2];
#pragma unroll
        for (int i = 0; i < 4; ++i) { m[i][0] = 0.f; m[i][1] = 0.f; }
#pragma unroll
        for (int p = 0; p < 32; ++p) {
            int idx = p ^ l31;
            float4 w0 = wp[idx];          // col = lane
            float4 w1 = wp[idx + 2048];   // col = 64+lane (offset 32 KB)
#pragma unroll
            for (int i = 0; i < 4; ++i) {
                float4 xv = sp[i * 32 + p];   // uniform addr -> broadcast
                m[i][0] += xv.x * w0.x + xv.y * w0.y + xv.z * w0.z + xv.w * w0.w;
                m[i][1] += xv.x * w1.x + xv.y * w1.y + xv.z * w1.z + xv.w * w1.w;
            }
        }
        // ---- batched reductions: 4 rows x {Sm,My,Di0,Di1,Dj0,Dj1,Sx} ----
        float red[28];
#pragma unroll
        for (int i = 0; i < 4; ++i) {
            red[i * 7 + 0] = m[i][0] * m[i][0] + m[i][1] * m[i][1];
            red[i * 7 + 1] = m[i][0] * e0 + m[i][1] * e1;
            red[i * 7 + 2] = m[i][0] * ai0;
            red[i * 7 + 3] = m[i][1] * ai1;
            red[i * 7 + 4] = m[i][0] * aj0;
            red[i * 7 + 5] = m[i][1] * aj1;
            red[i * 7 + 6] = px2[i];
        }
#pragma unroll
        for (int off = 32; off > 0; off >>= 1) {
#pragma unroll
            for (int j = 0; j < 28; ++j) red[j] += __shfl_xor(red[j], off, 64);
        }
        // ---- per-row analytic chain + stores ----
#pragma unroll
        for (int i = 0; i < 4; ++i) {
            int r = rb + i;
            if (r >= n) continue;
            float Sm  = red[i * 7 + 0];
            float My  = red[i * 7 + 1];
            float Di0 = red[i * 7 + 2];
            float Di1 = red[i * 7 + 3];
            float Dj0 = red[i * 7 + 4];
            float Dj1 = red[i * 7 + 5];
            float Sx  = red[i * 7 + 6];
            float xn = fmaxf(sqrtf(Sx), 1e-15f);
            float mxn = fmaxf(sqrtf(Sm), 1e-15f);
            float art = fatanh(fminf(xn, 1.f - 1e-7f));
            float tn = ftanh(__fdividef(mxn, xn) * art);
            float rho = (Sm == 0.f) ? 0.f : __fdividef(tn, mxn);
            float pn = (Sm == 0.f) ? 0.f : tn;
            if (pn > MAXN_F) { rho *= MAXN_F / pn; pn = MAXN_F; }
            float X2 = pn * pn, XY = rho * My;
            float ca = 1.f + 2.f * XY + y2v;
            float cb = 1.f - X2;
            float dn = fmaxf(1.f + 2.f * XY + X2 * y2v, 1e-15f);
            float Sh = __fdividef(ca * ca * X2 + 2.f * ca * cb * XY + cb * cb * y2v,
                                  dn * dn);
            float nraw = fmaxf(sqrtf(Sh), 1e-15f);
            float scp = 1.f, nh = nraw;
            if (nraw > MAXN_F) { scp = MAXN_F / nraw; nh = MAXN_F; }
            float g = __fdividef(fatanh(fminf(nh, 1.f - 1e-7f)), nh);
            float gs = __fdividef(g * scp, dn);
            float al = gs * ca * rho;
            float be = gs * cb;
            xtb[(size_t)r * DH + lane] = packbf(al * m[i][0] + be * e0,
                                               al * m[i][1] + be * e1);
            if (lane == 0) {
                reinterpret_cast<float2*>(ai)[r] =
                    make_float2(al * Di0 + be * Yi0, al * Di1 + be * Yi1);
                reinterpret_cast<float2*>(aj)[r] =
                    make_float2(al * Dj0 + be * Yj0, al * Dj1 + be * Yj1);
            }
        }
#pragma unroll
        for (int i = 0; i < 4; ++i) pc[i] = nc[i];
    }
    // ---- edge histogram tail ----
    {
        int perB = (E + NBLK - 1) / NBLK;
        int eb = blockIdx.x * perB;
        int ee = min(E, eb + perB);
        for (int e = eb + tid; e < ee; e += NTHR) atomicAdd(&deg[eidx[e]], 1);
    }
}

// ---------------- scan1: per-1024-chunk sums ----------------
__global__ __launch_bounds__(256) void scan1_k(const int* __restrict__ deg,
                                               int* __restrict__ bsum, int n) {
    int b = blockIdx.x, tid = threadIdx.x;
    int i0 = b * 1024 + tid * 4;
    int s = 0;
#pragma unroll
    for (int k = 0; k < 4; ++k)
        if (i0 + k < n) s += deg[i0 + k];
    s = wsumi(s);
    __shared__ int sm[4];
    if ((tid & 63) == 0) sm[tid >> 6] = s;
    __syncthreads();
    if (tid == 0) bsum[b] = sm[0] + sm[1] + sm[2] + sm[3];
}

// ---------------- scan23: top-level scan + rowptr/cursor ----------------
__global__ __launch_bounds__(256) void scan23_k(const int* __restrict__ deg,
                                                const int* __restrict__ bsum,
                                                int* __restrict__ rowptr,
                                                int* __restrict__ cursor,
                                                int n, int E, int nb) {
    int b = blockIdx.x, tid = threadIdx.x;
    __shared__ int sm2[256];
    int v = (tid < nb) ? bsum[tid] : 0;
    sm2[tid] = v;
    __syncthreads();
    for (int off = 1; off < 256; off <<= 1) {
        int u = (tid >= off) ? sm2[tid - off] : 0;
        __syncthreads();
        sm2[tid] += u;
        __syncthreads();
    }
    __shared__ int myoff;
    if (tid == 0) myoff = sm2[b] - bsum[b];
    __syncthreads();
    int i0 = b * 1024 + tid * 4;
    int d[4];
#pragma unroll
    for (int k = 0; k < 4; ++k) d[k] = (i0 + k < n) ? deg[i0 + k] : 0;
    int ts = d[0] + d[1] + d[2] + d[3];
    __shared__ int sm[256];
    sm[tid] = ts;
    __syncthreads();
    for (int off = 1; off < 256; off <<= 1) {
        int u = (tid >= off) ? sm[tid - off] : 0;
        __syncthreads();
        sm[tid] += u;
        __syncthreads();
    }
    int base = myoff + sm[tid] - ts;
    int pre = 0;
#pragma unroll
    for (int k = 0; k < 4; ++k) {
        if (i0 + k < n) {
            rowptr[i0 + k] = base + pre;
            cursor[i0 + k] = base + pre;
        }
        pre += d[k];
    }
    if (b == 0 && tid == 0) rowptr[n] = E;
}

// ---------------- CSR scatter ----------------
__global__ __launch_bounds__(256) void scatter_k(const int* __restrict__ eidx,
                                                 int* __restrict__ cursor,
                                                 int* __restrict__ csrc, int E) {
    int e = blockIdx.x * 256 + threadIdx.x;
    if (e >= E) return;
    int t = eidx[e], s = eidx[E + e];
    int pos = atomicAdd(&cursor[t], 1);
    csrc[pos] = s;
}

// ---------------- fused softmax + aggregation + HypAct ----------------
__global__ __launch_bounds__(256) void agg_fused_k(
    const int* __restrict__ rowptr, const int* __restrict__ csrc,
    const float* __restrict__ ai, const float* __restrict__ aj,
    const unsigned* __restrict__ xtb, float* __restrict__ out, int n) {
    int t = (blockIdx.x * 256 + threadIdx.x) >> 6;
    int lane = threadIdx.x & 63;
    if (t >= n) return;
    const int beg = rowptr[t];
    const int deg = rowptr[t + 1] - beg;
    const int cnt = deg + 1;  // + self loop
    float2 ait = reinterpret_cast<const float2*>(ai)[t];
    const float2* aj2 = reinterpret_cast<const float2*>(aj);
    float u;
    if (cnt <= 64) {
        // ---- single-pass fast path ----
        int s_ = t;
        if (lane < deg) s_ = csrc[beg + lane];
        float a0 = -1e30f, a1 = -1e30f;
        if (lane < cnt) {
            float2 av = aj2[s_];
            a0 = ait.x + av.x; a0 = a0 < 0.f ? 0.2f * a0 : a0;
            a1 = ait.y + av.y; a1 = a1 < 0.f ? 0.2f * a1 : a1;
        }
        float mx0 = wmax(a0), mx1 = wmax(a1);
        float e0 = (lane < cnt) ? expf(a0 - mx0) : 0.f;
        float e1 = (lane < cnt) ? expf(a1 - mx1) : 0.f;
        float den0 = wsum(e0), den1 = wsum(e1);
        float w0s = 0.5f * e0 / (den0 + 1e-16f);
        float w1s = 0.5f * e1 / (den1 + 1e-16f);
        float acc = 0.f;
        for (int j = 0; j < cnt; ++j) {
            int sj = __shfl(s_, j, 64);
            float w0 = __shfl(w0s, j, 64);
            float w1 = __shfl(w1s, j, 64);
            unsigned v = xtb[(size_t)sj * DH + lane];
            acc += w0 * __uint_as_float(v << 16) +
                   w1 * __uint_as_float(v & 0xffff0000u);
        }
        u = acc;
    } else {
        // ---- general two-pass path (rare: deg > 63) ----
        float mx0 = -1e30f, mx1 = -1e30f;
        for (int bs = 0; bs < cnt; bs += 64) {
            int idx = bs + lane;
            float a0 = -1e30f, a1 = -1e30f;
            if (idx < cnt) {
                int s = (idx < deg) ? csrc[beg + idx] : t;
                float2 av = aj2[s];
                a0 = ait.x + av.x; a0 = a0 < 0.f ? 0.2f * a0 : a0;
                a1 = ait.y + av.y; a1 = a1 < 0.f ? 0.2f * a1 : a1;
            }
            mx0 = fmaxf(mx0, a0);
            mx1 = fmaxf(mx1, a1);
        }
        mx0 = wmax(mx0);
        mx1 = wmax(mx1);
        float acc0 = 0.f, acc1 = 0.f, den0 = 0.f, den1 = 0.f;
        for (int bs = 0; bs < cnt; bs += 64) {
            int idx = bs + lane;
            int s = t;
            float e0 = 0.f, e1 = 0.f;
            if (idx < cnt) {
                s = (idx < deg) ? csrc[beg + idx] : t;
                float2 av = aj2[s];
                float a0 = ait.x + av.x; a0 = a0 < 0.f ? 0.2f * a0 : a0;
                float a1 = ait.y + av.y; a1 = a1 < 0.f ? 0.2f * a1 : a1;
                e0 = expf(a0 - mx0);
                e1 = expf(a1 - mx1);
            }
            den0 += e0;
            den1 += e1;
            int m = min(64, cnt - bs);
            for (int j = 0; j < m; ++j) {
                int sj = __shfl(s, j, 64);
                float w0 = __shfl(e0, j, 64);
                float w1 = __shfl(e1, j, 64);
                unsigned v = xtb[(size_t)sj * DH + lane];
                acc0 += w0 * __uint_as_float(v << 16);
                acc1 += w1 * __uint_as_float(v & 0xffff0000u);
            }
        }
        den0 = wsum(den0);
        den1 = wsum(den1);
        u = 0.5f * (acc0 / (den0 + 1e-16f) + acc1 / (den1 + 1e-16f));
    }
    // ---- HypAct: expmap0 -> proj -> logmap0 -> leaky -> expmap0 -> proj ----
    float Su = wsum(u * u);
    float nu = fmaxf(sqrtf(Su), 1e-15f);
    float e = tanhf(nu) * u / nu;
    float Se = wsum(e * e);
    float ne = fmaxf(sqrtf(Se), 1e-15f);
    if (ne > MAXN_F) e *= MAXN_F / ne;
    float Sh = wsum(e * e);
    float nh = fmaxf(sqrtf(Sh), 1e-15f);
    float g = atanhf(fminf(nh, 1.f - 1e-7f)) / nh;
    float ht = g * e;
    ht = ht < 0.f ? 0.01f * ht : ht;
    float St = wsum(ht * ht);
    float nt = fmaxf(sqrtf(St), 1e-15f);
    float o = tanhf(nt) * ht / nt;
    float So = wsum(o * o);
    float no = fmaxf(sqrtf(So), 1e-15f);
    if (no > MAXN_F) o *= MAXN_F / no;
    out[(size_t)t * DH + lane] = o;
}

extern "C" void kernel_launch(void* const* d_in, const int* in_sizes, int n_in,
                              void* d_out, int out_size, void* d_ws, size_t ws_size,
                              hipStream_t stream) {
    const float* x    = (const float*)d_in[0];
    const int*   eidx = (const int*)d_in[1];
    const float* W    = (const float*)d_in[2];
    const float* bias = (const float*)d_in[3];
    const float* atti = (const float*)d_in[4];
    const float* attj = (const float*)d_in[5];
    float* out = (float*)d_out;

    const int n = in_sizes[0] / DD;  // 100000
    const int E = in_sizes[1] / 2;   // 600000
    const size_t nf = (size_t)n;

    unsigned* xtb = (unsigned*)d_ws;            // n*64 dwords (bf16 pairs)
    float* ai  = (float*)(xtb + nf * DH);       // 2n
    float* aj  = ai + 2 * nf;                   // 2n
    int* deg    = (int*)(aj + 2 * nf);          // n
    int* rowptr = deg + nf;                     // n+1
    int* cursor = rowptr + nf + 1;              // n
    int* bsum   = cursor + nf;                  // 256
    int* csrc   = bsum + 256;                   // E

    const int nb = (n + 1023) / 1024;  // scan chunks (<=256)

    hipMemsetAsync(deg, 0, nf * sizeof(int), stream);
    gemm_node_k<<<NBLK, NTHR, 0, stream>>>(x, W, bias, atti, attj, eidx, deg,
                                           xtb, ai, aj, n, E);
    scan1_k<<<nb, 256, 0, stream>>>(deg, bsum, n);
    scan23_k<<<nb, 256, 0, stream>>>(deg, bsum, rowptr, cursor, n, E, nb);
    scatter_k<<<(E + 255) / 256, 256, 0, stream>>>(eidx, cursor, csrc, E);
    agg_fused_k<<<(n + 3) / 4, 256, 0, stream>>>(rowptr, csrc, ai, aj, xtb, out, n);
}

// Round 19
// 199.385 us; speedup vs baseline: 1.4725x; 1.4725x over previous
//
#include <hip/hip_runtime.h>
#include <hip/hip_bf16.h>
#include <math.h>

#define DD 128
#define DH 64
#define BM 64
#define MAXN_F (1.0f - 4e-3f)

typedef short s8v __attribute__((ext_vector_type(8)));   // 8 bf16 (4 VGPR)
typedef float f4v __attribute__((ext_vector_type(4)));   // MFMA accum

__device__ inline float wsum(float v) {
#pragma unroll
    for (int off = 32; off > 0; off >>= 1) v += __shfl_xor(v, off, 64);
    return v;
}
__device__ inline float wmax(float v) {
#pragma unroll
    for (int off = 32; off > 0; off >>= 1) v = fmaxf(v, __shfl_xor(v, off, 64));
    return v;
}
__device__ inline int wsumi(int v) {
#pragma unroll
    for (int off = 32; off > 0; off >>= 1) v += __shfl_xor(v, off, 64);
    return v;
}
__device__ inline unsigned short f2bf16(float x) {
    unsigned u = __float_as_uint(x);
    u += 0x7fffu + ((u >> 16) & 1u);   // RNE
    return (unsigned short)(u >> 16);
}
__device__ inline unsigned packbf(float a, float b) {
    return (unsigned)f2bf16(a) | ((unsigned)f2bf16(b) << 16);
}
__device__ inline float fatanh(float z) {
    return 0.5f * __logf(__fdividef(1.f + z, 1.f - z));
}
__device__ inline float ftanh(float y) {
    y = fminf(y, 10.f);
    float e = __expf(2.f * y);
    return __fdividef(e - 1.f, e + 1.f);
}

// ---- MFMA GEMM (mx = x@W^T, bf16 in / f32 acc) + analytic epilogue ------
// 256 thr = 4 waves, 64 rows/block. W+x staged bf16 in LDS as 16B k-chunks,
// XOR-swizzled (chunk ^ row&15). Wave wv: rows wv*16..+15, all 128 cols:
// 8 f32x4 acc, 32 MFMA. Epilogue: per-row scalars via 16-lane shfl.
__global__ __launch_bounds__(256) void gemm_node_k(
    const float* __restrict__ x, const float* __restrict__ W,
    const float* __restrict__ bias,
    const float* __restrict__ atti, const float* __restrict__ attj,
    const int* __restrict__ eidx, int* __restrict__ deg,
    unsigned* __restrict__ xtb, float* __restrict__ ai, float* __restrict__ aj,
    int n, int E) {
    __shared__ short wl[128 * 128];   // 32 KB bf16 W
    __shared__ short xl[BM * 128];    // 16 KB bf16 x tile
    __shared__ float hbl[128];
    __shared__ float sxq[BM];
    const int row0 = blockIdx.x * BM;
    const int tid = threadIdx.x;
    const int wv = tid >> 6;
    const int lane = tid & 63;
    const int l15 = lane & 15;
    const int g = lane >> 4;
    const float4* x4 = reinterpret_cast<const float4*>(x);
    const float4* W4 = reinterpret_cast<const float4*>(W);
    s8v* wl8 = reinterpret_cast<s8v*>(wl);
    s8v* xl8 = reinterpret_cast<s8v*>(xl);
    // ---- stage W (fp32 -> bf16 chunks, swizzled) ----
#pragma unroll
    for (int i = 0; i < 8; ++i) {
        int s = tid + i * 256;            // 0..2047
        int row = s >> 4, ch = s & 15;
        float4 f0 = W4[row * 32 + ch * 2];
        float4 f1 = W4[row * 32 + ch * 2 + 1];
        s8v hv;
        hv[0] = (short)f2bf16(f0.x); hv[1] = (short)f2bf16(f0.y);
        hv[2] = (short)f2bf16(f0.z); hv[3] = (short)f2bf16(f0.w);
        hv[4] = (short)f2bf16(f1.x); hv[5] = (short)f2bf16(f1.y);
        hv[6] = (short)f2bf16(f1.z); hv[7] = (short)f2bf16(f1.w);
        wl8[row * 16 + (ch ^ (row & 15))] = hv;
    }
    // ---- stage x tile + |x|^2 per row ----
#pragma unroll
    for (int i = 0; i < 4; ++i) {
        int s = tid + i * 256;            // 0..1023
        int r = s >> 4, ch = s & 15;
        int grow = row0 + r;
        float4 f0 = make_float4(0.f, 0.f, 0.f, 0.f), f1 = f0;
        if (grow < n) {
            f0 = x4[(size_t)grow * 32 + ch * 2];
            f1 = x4[(size_t)grow * 32 + ch * 2 + 1];
        }
        s8v hv;
        hv[0] = (short)f2bf16(f0.x); hv[1] = (short)f2bf16(f0.y);
        hv[2] = (short)f2bf16(f0.z); hv[3] = (short)f2bf16(f0.w);
        hv[4] = (short)f2bf16(f1.x); hv[5] = (short)f2bf16(f1.y);
        hv[6] = (short)f2bf16(f1.z); hv[7] = (short)f2bf16(f1.w);
        xl8[r * 16 + (ch ^ (r & 15))] = hv;
        float px = f0.x * f0.x + f0.y * f0.y + f0.z * f0.z + f0.w * f0.w +
                   f1.x * f1.x + f1.y * f1.y + f1.z * f1.z + f1.w * f1.w;
#pragma unroll
        for (int off = 8; off > 0; off >>= 1) px += __shfl_xor(px, off, 16);
        if ((tid & 15) == 0) sxq[r] = px;
    }
    // ---- per-wave bias/att pipeline (registers) ----
    float b0 = bias[lane], b1 = bias[64 + lane];
    float ai0 = atti[lane], ai1 = atti[64 + lane];
    float aj0 = attj[lane], aj1 = attj[64 + lane];
    float Sb = wsum(b0 * b0 + b1 * b1);
    float nb_ = fmaxf(sqrtf(Sb), 1e-15f);
    float th = tanhf(nb_) / nb_;
    float e0 = th * b0, e1 = th * b1;
    float Se = wsum(e0 * e0 + e1 * e1);
    float ne = fmaxf(sqrtf(Se), 1e-15f);
    if (ne > MAXN_F) { float sc = MAXN_F / ne; e0 *= sc; e1 *= sc; }
    float y2v = wsum(e0 * e0 + e1 * e1);
    float Yi0 = wsum(e0 * ai0), Yi1 = wsum(e1 * ai1);
    float Yj0 = wsum(e0 * aj0), Yj1 = wsum(e1 * aj1);
    if (tid < 64) { hbl[tid] = e0; hbl[64 + tid] = e1; }
    __syncthreads();
    // ---- per-lane col-vectors (col c = ct*16 + l15) ----
    float hbv[8], av[8], bv[8];
#pragma unroll
    for (int ct = 0; ct < 8; ++ct) {
        int c = ct * 16 + l15;
        hbv[ct] = hbl[c];
        av[ct] = atti[c];
        bv[ct] = attj[c];
    }
    // ---- MFMA: wave rows wv*16..+15, cols 0..127 ----
    f4v acc[8];
#pragma unroll
    for (int ct = 0; ct < 8; ++ct) acc[ct] = (f4v){0.f, 0.f, 0.f, 0.f};
#pragma unroll
    for (int kc = 0; kc < 4; ++kc) {
        s8v a = xl8[(wv * 16 + l15) * 16 + ((kc * 4 + g) ^ l15)];
#pragma unroll
        for (int ct = 0; ct < 8; ++ct) {
            s8v b = wl8[(ct * 16 + l15) * 16 + ((kc * 4 + g) ^ l15)];
            acc[ct] = __builtin_amdgcn_mfma_f32_16x16x32_bf16(a, b, acc[ct], 0, 0, 0);
        }
    }
    // ---- per-row scalar reductions (16-lane groups own a row's cols) ----
    float red[24];
#pragma unroll
    for (int reg = 0; reg < 4; ++reg) {
        float sm = 0.f, my = 0.f, d0 = 0.f, d1 = 0.f, f0 = 0.f, f1 = 0.f;
#pragma unroll
        for (int ct = 0; ct < 8; ++ct) {
            float v = acc[ct][reg];
            sm += v * v;
            my += v * hbv[ct];
            if (ct < 4) { d0 += v * av[ct]; f0 += v * bv[ct]; }
            else        { d1 += v * av[ct]; f1 += v * bv[ct]; }
        }
        red[reg * 6 + 0] = sm; red[reg * 6 + 1] = my;
        red[reg * 6 + 2] = d0; red[reg * 6 + 3] = d1;
        red[reg * 6 + 4] = f0; red[reg * 6 + 5] = f1;
    }
#pragma unroll
    for (int off = 8; off > 0; off >>= 1) {
#pragma unroll
        for (int j = 0; j < 24; ++j) red[j] += __shfl_xor(red[j], off, 16);
    }
    // ---- analytic chain + stores (lane handles its group's 4 rows) ----
#pragma unroll
    for (int reg = 0; reg < 4; ++reg) {
        int rr = wv * 16 + g * 4 + reg;
        int gr = row0 + rr;
        float Sx  = sxq[rr];
        float Sm  = red[reg * 6 + 0];
        float My  = red[reg * 6 + 1];
        float Di0 = red[reg * 6 + 2];
        float Di1 = red[reg * 6 + 3];
        float Dj0 = red[reg * 6 + 4];
        float Dj1 = red[reg * 6 + 5];
        float xn = fmaxf(sqrtf(Sx), 1e-15f);
        float mxn = fmaxf(sqrtf(Sm), 1e-15f);
        float art = fatanh(fminf(xn, 1.f - 1e-7f));
        float tn = ftanh(__fdividef(mxn, xn) * art);
        float rho = (Sm == 0.f) ? 0.f : __fdividef(tn, mxn);
        float pn = (Sm == 0.f) ? 0.f : tn;
        if (pn > MAXN_F) { rho *= MAXN_F / pn; pn = MAXN_F; }
        float X2 = pn * pn, XY = rho * My;
        float ca = 1.f + 2.f * XY + y2v;
        float cb = 1.f - X2;
        float dn = fmaxf(1.f + 2.f * XY + X2 * y2v, 1e-15f);
        float Sh = __fdividef(ca * ca * X2 + 2.f * ca * cb * XY + cb * cb * y2v,
                              dn * dn);
        float nraw = fmaxf(sqrtf(Sh), 1e-15f);
        float scp = 1.f, nh = nraw;
        if (nraw > MAXN_F) { scp = MAXN_F / nraw; nh = MAXN_F; }
        float gg = __fdividef(fatanh(fminf(nh, 1.f - 1e-7f)), nh);
        float gs = __fdividef(gg * scp, dn);
        float al = gs * ca * rho;
        float be = gs * cb;
        if (gr < n) {
#pragma unroll
            for (int ct = 0; ct < 4; ++ct) {
                xtb[(size_t)gr * DH + ct * 16 + l15] =
                    packbf(al * acc[ct][reg] + be * hbv[ct],
                           al * acc[ct + 4][reg] + be * hbv[ct + 4]);
            }
            if (l15 == 0) {
                reinterpret_cast<float2*>(ai)[gr] =
                    make_float2(al * Di0 + be * Yi0, al * Di1 + be * Yi1);
                reinterpret_cast<float2*>(aj)[gr] =
                    make_float2(al * Dj0 + be * Yj0, al * Dj1 + be * Yj1);
            }
        }
    }
    // ---- edge histogram tail ----
    {
        int perB = (E + gridDim.x - 1) / gridDim.x;
        int eb = blockIdx.x * perB;
        int ee = min(E, eb + perB);
        for (int e = eb + tid; e < ee; e += 256) atomicAdd(&deg[eidx[e]], 1);
    }
}

// ---------------- scan1: per-1024-chunk sums ----------------
__global__ __launch_bounds__(256) void scan1_k(const int* __restrict__ deg,
                                               int* __restrict__ bsum, int n) {
    int b = blockIdx.x, tid = threadIdx.x;
    int i0 = b * 1024 + tid * 4;
    int s = 0;
#pragma unroll
    for (int k = 0; k < 4; ++k)
        if (i0 + k < n) s += deg[i0 + k];
    s = wsumi(s);
    __shared__ int sm[4];
    if ((tid & 63) == 0) sm[tid >> 6] = s;
    __syncthreads();
    if (tid == 0) bsum[b] = sm[0] + sm[1] + sm[2] + sm[3];
}

// ---------------- scan23: top-level scan + rowptr/cursor ----------------
__global__ __launch_bounds__(256) void scan23_k(const int* __restrict__ deg,
                                                const int* __restrict__ bsum,
                                                int* __restrict__ rowptr,
                                                int* __restrict__ cursor,
                                                int n, int E, int nb) {
    int b = blockIdx.x, tid = threadIdx.x;
    __shared__ int sm2[256];
    int v = (tid < nb) ? bsum[tid] : 0;
    sm2[tid] = v;
    __syncthreads();
    for (int off = 1; off < 256; off <<= 1) {
        int u = (tid >= off) ? sm2[tid - off] : 0;
        __syncthreads();
        sm2[tid] += u;
        __syncthreads();
    }
    __shared__ int myoff;
    if (tid == 0) myoff = sm2[b] - bsum[b];
    __syncthreads();
    int i0 = b * 1024 + tid * 4;
    int d[4];
#pragma unroll
    for (int k = 0; k < 4; ++k) d[k] = (i0 + k < n) ? deg[i0 + k] : 0;
    int ts = d[0] + d[1] + d[2] + d[3];
    __shared__ int sm[256];
    sm[tid] = ts;
    __syncthreads();
    for (int off = 1; off < 256; off <<= 1) {
        int u = (tid >= off) ? sm[tid - off] : 0;
        __syncthreads();
        sm[tid] += u;
        __syncthreads();
    }
    int base = myoff + sm[tid] - ts;
    int pre = 0;
#pragma unroll
    for (int k = 0; k < 4; ++k) {
        if (i0 + k < n) {
            rowptr[i0 + k] = base + pre;
            cursor[i0 + k] = base + pre;
        }
        pre += d[k];
    }
    if (b == 0 && tid == 0) rowptr[n] = E;
}

// ---------------- CSR scatter ----------------
__global__ __launch_bounds__(256) void scatter_k(const int* __restrict__ eidx,
                                                 int* __restrict__ cursor,
                                                 int* __restrict__ csrc, int E) {
    int e = blockIdx.x * 256 + threadIdx.x;
    if (e >= E) return;
    int t = eidx[e], s = eidx[E + e];
    int pos = atomicAdd(&cursor[t], 1);
    csrc[pos] = s;
}

// ---------------- fused softmax + aggregation + HypAct ----------------
__global__ __launch_bounds__(256) void agg_fused_k(
    const int* __restrict__ rowptr, const int* __restrict__ csrc,
    const float* __restrict__ ai, const float* __restrict__ aj,
    const unsigned* __restrict__ xtb, float* __restrict__ out, int n) {
    int t = (blockIdx.x * 256 + threadIdx.x) >> 6;
    int lane = threadIdx.x & 63;
    if (t >= n) return;
    const int beg = rowptr[t];
    const int deg = rowptr[t + 1] - beg;
    const int cnt = deg + 1;  // + self loop
    float2 ait = reinterpret_cast<const float2*>(ai)[t];
    const float2* aj2 = reinterpret_cast<const float2*>(aj);
    float u;
    if (cnt <= 64) {
        int s_ = t;
        if (lane < deg) s_ = csrc[beg + lane];
        float a0 = -1e30f, a1 = -1e30f;
        if (lane < cnt) {
            float2 av = aj2[s_];
            a0 = ait.x + av.x; a0 = a0 < 0.f ? 0.2f * a0 : a0;
            a1 = ait.y + av.y; a1 = a1 < 0.f ? 0.2f * a1 : a1;
        }
        float mx0 = wmax(a0), mx1 = wmax(a1);
        float e0 = (lane < cnt) ? expf(a0 - mx0) : 0.f;
        float e1 = (lane < cnt) ? expf(a1 - mx1) : 0.f;
        float den0 = wsum(e0), den1 = wsum(e1);
        float w0s = 0.5f * e0 / (den0 + 1e-16f);
        float w1s = 0.5f * e1 / (den1 + 1e-16f);
        float acc = 0.f;
        for (int j = 0; j < cnt; ++j) {
            int sj = __shfl(s_, j, 64);
            float w0 = __shfl(w0s, j, 64);
            float w1 = __shfl(w1s, j, 64);
            unsigned v = xtb[(size_t)sj * DH + lane];
            acc += w0 * __uint_as_float(v << 16) +
                   w1 * __uint_as_float(v & 0xffff0000u);
        }
        u = acc;
    } else {
        float mx0 = -1e30f, mx1 = -1e30f;
        for (int bs = 0; bs < cnt; bs += 64) {
            int idx = bs + lane;
            float a0 = -1e30f, a1 = -1e30f;
            if (idx < cnt) {
                int s = (idx < deg) ? csrc[beg + idx] : t;
                float2 av = aj2[s];
                a0 = ait.x + av.x; a0 = a0 < 0.f ? 0.2f * a0 : a0;
                a1 = ait.y + av.y; a1 = a1 < 0.f ? 0.2f * a1 : a1;
            }
            mx0 = fmaxf(mx0, a0);
            mx1 = fmaxf(mx1, a1);
        }
        mx0 = wmax(mx0);
        mx1 = wmax(mx1);
        float acc0 = 0.f, acc1 = 0.f, den0 = 0.f, den1 = 0.f;
        for (int bs = 0; bs < cnt; bs += 64) {
            int idx = bs + lane;
            int s = t;
            float e0 = 0.f, e1 = 0.f;
            if (idx < cnt) {
                s = (idx < deg) ? csrc[beg + idx] : t;
                float2 av = aj2[s];
                float a0 = ait.x + av.x; a0 = a0 < 0.f ? 0.2f * a0 : a0;
                float a1 = ait.y + av.y; a1 = a1 < 0.f ? 0.2f * a1 : a1;
                e0 = expf(a0 - mx0);
                e1 = expf(a1 - mx1);
            }
            den0 += e0;
            den1 += e1;
            int m = min(64, cnt - bs);
            for (int j = 0; j < m; ++j) {
                int sj = __shfl(s, j, 64);
                float w0 = __shfl(e0, j, 64);
                float w1 = __shfl(e1, j, 64);
                unsigned v = xtb[(size_t)sj * DH + lane];
                acc0 += w0 * __uint_as_float(v << 16);
                acc1 += w1 * __uint_as_float(v & 0xffff0000u);
            }
        }
        den0 = wsum(den0);
        den1 = wsum(den1);
        u = 0.5f * (acc0 / (den0 + 1e-16f) + acc1 / (den1 + 1e-16f));
    }
    // ---- HypAct ----
    float Su = wsum(u * u);
    float nu = fmaxf(sqrtf(Su), 1e-15f);
    float e = tanhf(nu) * u / nu;
    float Se = wsum(e * e);
    float ne = fmaxf(sqrtf(Se), 1e-15f);
    if (ne > MAXN_F) e *= MAXN_F / ne;
    float Sh = wsum(e * e);
    float nh = fmaxf(sqrtf(Sh), 1e-15f);
    float g = atanhf(fminf(nh, 1.f - 1e-7f)) / nh;
    float ht = g * e;
    ht = ht < 0.f ? 0.01f * ht : ht;
    float St = wsum(ht * ht);
    float nt = fmaxf(sqrtf(St), 1e-15f);
    float o = tanhf(nt) * ht / nt;
    float So = wsum(o * o);
    float no = fmaxf(sqrtf(So), 1e-15f);
    if (no > MAXN_F) o *= MAXN_F / no;
    out[(size_t)t * DH + lane] = o;
}

extern "C" void kernel_launch(void* const* d_in, const int* in_sizes, int n_in,
                              void* d_out, int out_size, void* d_ws, size_t ws_size,
                              hipStream_t stream) {
    const float* x    = (const float*)d_in[0];
    const int*   eidx = (const int*)d_in[1];
    const float* W    = (const float*)d_in[2];
    const float* bias = (const float*)d_in[3];
    const float* atti = (const float*)d_in[4];
    const float* attj = (const float*)d_in[5];
    float* out = (float*)d_out;

    const int n = in_sizes[0] / DD;  // 100000
    const int E = in_sizes[1] / 2;   // 600000
    const size_t nf = (size_t)n;

    unsigned* xtb = (unsigned*)d_ws;            // n*64 dwords (bf16 pairs)
    float* ai  = (float*)(xtb + nf * DH);       // 2n
    float* aj  = ai + 2 * nf;                   // 2n
    int* deg    = (int*)(aj + 2 * nf);          // n
    int* rowptr = deg + nf;                     // n+1
    int* cursor = rowptr + nf + 1;              // n
    int* bsum   = cursor + nf;                  // 256
    int* csrc   = bsum + 256;                   // E

    const int nb = (n + 1023) / 1024;  // scan chunks (<=256)
    const int ngemm = (n + BM - 1) / BM;

    hipMemsetAsync(deg, 0, nf * sizeof(int), stream);
    gemm_node_k<<<ngemm, 256, 0, stream>>>(x, W, bias, atti, attj, eidx, deg,
                                           xtb, ai, aj, n, E);
    scan1_k<<<nb, 256, 0, stream>>>(deg, bsum, n);
    scan23_k<<<nb, 256, 0, stream>>>(deg, bsum, rowptr, cursor, n, E, nb);
    scatter_k<<<(E + 255) / 256, 256, 0, stream>>>(eidx, cursor, csrc, E);
    agg_fused_k<<<(n + 3) / 4, 256, 0, stream>>>(rowptr, csrc, ai, aj, xtb, out, n);
}

// Round 20
// 178.926 us; speedup vs baseline: 1.6409x; 1.1143x over previous
//
#include <hip/hip_runtime.h>
#include <hip/hip_bf16.h>
#include <math.h>

#define DD 128
#define DH 64
#define BM 64
#define MAXN_F (1.0f - 4e-3f)

typedef short s8v __attribute__((ext_vector_type(8)));   // 8 bf16 (4 VGPR)
typedef float f4v __attribute__((ext_vector_type(4)));   // MFMA accum

__device__ inline float wsum(float v) {
#pragma unroll
    for (int off = 32; off > 0; off >>= 1) v += __shfl_xor(v, off, 64);
    return v;
}
__device__ inline int wsumi(int v) {
#pragma unroll
    for (int off = 32; off > 0; off >>= 1) v += __shfl_xor(v, off, 64);
    return v;
}
__device__ inline unsigned short f2bf16(float x) {
    unsigned u = __float_as_uint(x);
    u += 0x7fffu + ((u >> 16) & 1u);   // RNE
    return (unsigned short)(u >> 16);
}
__device__ inline unsigned packbf(float a, float b) {
    return (unsigned)f2bf16(a) | ((unsigned)f2bf16(b) << 16);
}
__device__ inline float fatanh(float z) {
    return 0.5f * __logf(__fdividef(1.f + z, 1.f - z));
}
__device__ inline float ftanh(float y) {
    y = fminf(y, 10.f);
    float e = __expf(2.f * y);
    return __fdividef(e - 1.f, e + 1.f);
}

// ---- MFMA GEMM (mx = x@W^T, bf16 in / f32 acc) + analytic epilogue ------
__global__ __launch_bounds__(256) void gemm_node_k(
    const float* __restrict__ x, const float* __restrict__ W,
    const float* __restrict__ bias,
    const float* __restrict__ atti, const float* __restrict__ attj,
    const int* __restrict__ eidx, int* __restrict__ deg,
    unsigned* __restrict__ xtb, float* __restrict__ ai, float* __restrict__ aj,
    int n, int E) {
    __shared__ short wl[128 * 128];   // 32 KB bf16 W
    __shared__ short xl[BM * 128];    // 16 KB bf16 x tile
    __shared__ float hbl[128];
    __shared__ float sxq[BM];
    const int row0 = blockIdx.x * BM;
    const int tid = threadIdx.x;
    const int wv = tid >> 6;
    const int lane = tid & 63;
    const int l15 = lane & 15;
    const int g = lane >> 4;
    const float4* x4 = reinterpret_cast<const float4*>(x);
    const float4* W4 = reinterpret_cast<const float4*>(W);
    s8v* wl8 = reinterpret_cast<s8v*>(wl);
    s8v* xl8 = reinterpret_cast<s8v*>(xl);
    // ---- stage W (fp32 -> bf16 chunks, swizzled) ----
#pragma unroll
    for (int i = 0; i < 8; ++i) {
        int s = tid + i * 256;            // 0..2047
        int row = s >> 4, ch = s & 15;
        float4 f0 = W4[row * 32 + ch * 2];
        float4 f1 = W4[row * 32 + ch * 2 + 1];
        s8v hv;
        hv[0] = (short)f2bf16(f0.x); hv[1] = (short)f2bf16(f0.y);
        hv[2] = (short)f2bf16(f0.z); hv[3] = (short)f2bf16(f0.w);
        hv[4] = (short)f2bf16(f1.x); hv[5] = (short)f2bf16(f1.y);
        hv[6] = (short)f2bf16(f1.z); hv[7] = (short)f2bf16(f1.w);
        wl8[row * 16 + (ch ^ (row & 15))] = hv;
    }
    // ---- stage x tile + |x|^2 per row ----
#pragma unroll
    for (int i = 0; i < 4; ++i) {
        int s = tid + i * 256;            // 0..1023
        int r = s >> 4, ch = s & 15;
        int grow = row0 + r;
        float4 f0 = make_float4(0.f, 0.f, 0.f, 0.f), f1 = f0;
        if (grow < n) {
            f0 = x4[(size_t)grow * 32 + ch * 2];
            f1 = x4[(size_t)grow * 32 + ch * 2 + 1];
        }
        s8v hv;
        hv[0] = (short)f2bf16(f0.x); hv[1] = (short)f2bf16(f0.y);
        hv[2] = (short)f2bf16(f0.z); hv[3] = (short)f2bf16(f0.w);
        hv[4] = (short)f2bf16(f1.x); hv[5] = (short)f2bf16(f1.y);
        hv[6] = (short)f2bf16(f1.z); hv[7] = (short)f2bf16(f1.w);
        xl8[r * 16 + (ch ^ (r & 15))] = hv;
        float px = f0.x * f0.x + f0.y * f0.y + f0.z * f0.z + f0.w * f0.w +
                   f1.x * f1.x + f1.y * f1.y + f1.z * f1.z + f1.w * f1.w;
#pragma unroll
        for (int off = 8; off > 0; off >>= 1) px += __shfl_xor(px, off, 16);
        if ((tid & 15) == 0) sxq[r] = px;
    }
    // ---- per-wave bias/att pipeline (registers) ----
    float b0 = bias[lane], b1 = bias[64 + lane];
    float ai0 = atti[lane], ai1 = atti[64 + lane];
    float aj0 = attj[lane], aj1 = attj[64 + lane];
    float Sb = wsum(b0 * b0 + b1 * b1);
    float nb_ = fmaxf(sqrtf(Sb), 1e-15f);
    float th = tanhf(nb_) / nb_;
    float e0 = th * b0, e1 = th * b1;
    float Se = wsum(e0 * e0 + e1 * e1);
    float ne = fmaxf(sqrtf(Se), 1e-15f);
    if (ne > MAXN_F) { float sc = MAXN_F / ne; e0 *= sc; e1 *= sc; }
    float y2v = wsum(e0 * e0 + e1 * e1);
    float Yi0 = wsum(e0 * ai0), Yi1 = wsum(e1 * ai1);
    float Yj0 = wsum(e0 * aj0), Yj1 = wsum(e1 * aj1);
    if (tid < 64) { hbl[tid] = e0; hbl[64 + tid] = e1; }
    __syncthreads();
    // ---- per-lane col-vectors (col c = ct*16 + l15) ----
    float hbv[8], av[8], bv[8];
#pragma unroll
    for (int ct = 0; ct < 8; ++ct) {
        int c = ct * 16 + l15;
        hbv[ct] = hbl[c];
        av[ct] = atti[c];
        bv[ct] = attj[c];
    }
    // ---- MFMA: wave rows wv*16..+15, cols 0..127 ----
    f4v acc[8];
#pragma unroll
    for (int ct = 0; ct < 8; ++ct) acc[ct] = (f4v){0.f, 0.f, 0.f, 0.f};
#pragma unroll
    for (int kc = 0; kc < 4; ++kc) {
        s8v a = xl8[(wv * 16 + l15) * 16 + ((kc * 4 + g) ^ l15)];
#pragma unroll
        for (int ct = 0; ct < 8; ++ct) {
            s8v b = wl8[(ct * 16 + l15) * 16 + ((kc * 4 + g) ^ l15)];
            acc[ct] = __builtin_amdgcn_mfma_f32_16x16x32_bf16(a, b, acc[ct], 0, 0, 0);
        }
    }
    // ---- per-row scalar reductions (16-lane groups own a row's cols) ----
    float red[24];
#pragma unroll
    for (int reg = 0; reg < 4; ++reg) {
        float sm = 0.f, my = 0.f, d0 = 0.f, d1 = 0.f, f0 = 0.f, f1 = 0.f;
#pragma unroll
        for (int ct = 0; ct < 8; ++ct) {
            float v = acc[ct][reg];
            sm += v * v;
            my += v * hbv[ct];
            if (ct < 4) { d0 += v * av[ct]; f0 += v * bv[ct]; }
            else        { d1 += v * av[ct]; f1 += v * bv[ct]; }
        }
        red[reg * 6 + 0] = sm; red[reg * 6 + 1] = my;
        red[reg * 6 + 2] = d0; red[reg * 6 + 3] = d1;
        red[reg * 6 + 4] = f0; red[reg * 6 + 5] = f1;
    }
#pragma unroll
    for (int off = 8; off > 0; off >>= 1) {
#pragma unroll
        for (int j = 0; j < 24; ++j) red[j] += __shfl_xor(red[j], off, 16);
    }
    // ---- analytic chain + stores ----
#pragma unroll
    for (int reg = 0; reg < 4; ++reg) {
        int rr = wv * 16 + g * 4 + reg;
        int gr = row0 + rr;
        float Sx  = sxq[rr];
        float Sm  = red[reg * 6 + 0];
        float My  = red[reg * 6 + 1];
        float Di0 = red[reg * 6 + 2];
        float Di1 = red[reg * 6 + 3];
        float Dj0 = red[reg * 6 + 4];
        float Dj1 = red[reg * 6 + 5];
        float xn = fmaxf(sqrtf(Sx), 1e-15f);
        float mxn = fmaxf(sqrtf(Sm), 1e-15f);
        float art = fatanh(fminf(xn, 1.f - 1e-7f));
        float tn = ftanh(__fdividef(mxn, xn) * art);
        float rho = (Sm == 0.f) ? 0.f : __fdividef(tn, mxn);
        float pn = (Sm == 0.f) ? 0.f : tn;
        if (pn > MAXN_F) { rho *= MAXN_F / pn; pn = MAXN_F; }
        float X2 = pn * pn, XY = rho * My;
        float ca = 1.f + 2.f * XY + y2v;
        float cb = 1.f - X2;
        float dn = fmaxf(1.f + 2.f * XY + X2 * y2v, 1e-15f);
        float Sh = __fdividef(ca * ca * X2 + 2.f * ca * cb * XY + cb * cb * y2v,
                              dn * dn);
        float nraw = fmaxf(sqrtf(Sh), 1e-15f);
        float scp = 1.f, nh = nraw;
        if (nraw > MAXN_F) { scp = MAXN_F / nraw; nh = MAXN_F; }
        float gg = __fdividef(fatanh(fminf(nh, 1.f - 1e-7f)), nh);
        float gs = __fdividef(gg * scp, dn);
        float al = gs * ca * rho;
        float be = gs * cb;
        if (gr < n) {
#pragma unroll
            for (int ct = 0; ct < 4; ++ct) {
                xtb[(size_t)gr * DH + ct * 16 + l15] =
                    packbf(al * acc[ct][reg] + be * hbv[ct],
                           al * acc[ct + 4][reg] + be * hbv[ct + 4]);
            }
            if (l15 == 0) {
                reinterpret_cast<float2*>(ai)[gr] =
                    make_float2(al * Di0 + be * Yi0, al * Di1 + be * Yi1);
                reinterpret_cast<float2*>(aj)[gr] =
                    make_float2(al * Dj0 + be * Yj0, al * Dj1 + be * Yj1);
            }
        }
    }
    // ---- edge histogram tail ----
    {
        int perB = (E + gridDim.x - 1) / gridDim.x;
        int eb = blockIdx.x * perB;
        int ee = min(E, eb + perB);
        for (int e = eb + tid; e < ee; e += 256) atomicAdd(&deg[eidx[e]], 1);
    }
}

// ---------------- scan1: per-1024-chunk sums ----------------
__global__ __launch_bounds__(256) void scan1_k(const int* __restrict__ deg,
                                               int* __restrict__ bsum, int n) {
    int b = blockIdx.x, tid = threadIdx.x;
    int i0 = b * 1024 + tid * 4;
    int s = 0;
#pragma unroll
    for (int k = 0; k < 4; ++k)
        if (i0 + k < n) s += deg[i0 + k];
    s = wsumi(s);
    __shared__ int sm[4];
    if ((tid & 63) == 0) sm[tid >> 6] = s;
    __syncthreads();
    if (tid == 0) bsum[b] = sm[0] + sm[1] + sm[2] + sm[3];
}

// ---------------- scan23: top-level scan + rowptr/cursor ----------------
__global__ __launch_bounds__(256) void scan23_k(const int* __restrict__ deg,
                                                const int* __restrict__ bsum,
                                                int* __restrict__ rowptr,
                                                int* __restrict__ cursor,
                                                int n, int E, int nb) {
    int b = blockIdx.x, tid = threadIdx.x;
    __shared__ int sm2[256];
    int v = (tid < nb) ? bsum[tid] : 0;
    sm2[tid] = v;
    __syncthreads();
    for (int off = 1; off < 256; off <<= 1) {
        int u = (tid >= off) ? sm2[tid - off] : 0;
        __syncthreads();
        sm2[tid] += u;
        __syncthreads();
    }
    __shared__ int myoff;
    if (tid == 0) myoff = sm2[b] - bsum[b];
    __syncthreads();
    int i0 = b * 1024 + tid * 4;
    int d[4];
#pragma unroll
    for (int k = 0; k < 4; ++k) d[k] = (i0 + k < n) ? deg[i0 + k] : 0;
    int ts = d[0] + d[1] + d[2] + d[3];
    __shared__ int sm[256];
    sm[tid] = ts;
    __syncthreads();
    for (int off = 1; off < 256; off <<= 1) {
        int u = (tid >= off) ? sm[tid - off] : 0;
        __syncthreads();
        sm[tid] += u;
        __syncthreads();
    }
    int base = myoff + sm[tid] - ts;
    int pre = 0;
#pragma unroll
    for (int k = 0; k < 4; ++k) {
        if (i0 + k < n) {
            rowptr[i0 + k] = base + pre;
            cursor[i0 + k] = base + pre;
        }
        pre += d[k];
    }
    if (b == 0 && tid == 0) rowptr[n] = E;
}

// ---------------- CSR scatter ----------------
__global__ __launch_bounds__(256) void scatter_k(const int* __restrict__ eidx,
                                                 int* __restrict__ cursor,
                                                 int* __restrict__ csrc, int E) {
    int e = blockIdx.x * 256 + threadIdx.x;
    if (e >= E) return;
    int t = eidx[e], s = eidx[E + e];
    int pos = atomicAdd(&cursor[t], 1);
    csrc[pos] = s;
}

// ---------------- fused softmax + aggregation + HypAct (lean) ------------
// No max-subtraction (logits bounded |a|<~6.2); analytic norm tracking:
// only 2 wave reductions in HypAct; fast transcendentals.
__global__ __launch_bounds__(256) void agg_fused_k(
    const int* __restrict__ rowptr, const int* __restrict__ csrc,
    const float* __restrict__ ai, const float* __restrict__ aj,
    const unsigned* __restrict__ xtb, float* __restrict__ out, int n) {
    int t = (blockIdx.x * 256 + threadIdx.x) >> 6;
    int lane = threadIdx.x & 63;
    if (t >= n) return;
    const int beg = rowptr[t];
    const int deg = rowptr[t + 1] - beg;
    const int cnt = deg + 1;  // + self loop
    float2 ait = reinterpret_cast<const float2*>(ai)[t];
    const float2* aj2 = reinterpret_cast<const float2*>(aj);
    float u;
    if (cnt <= 64) {
        // ---- single-pass fast path ----
        int s_ = t;
        if (lane < deg) s_ = csrc[beg + lane];
        float e0 = 0.f, e1 = 0.f;
        if (lane < cnt) {
            float2 av = aj2[s_];
            float a0 = ait.x + av.x; a0 = a0 < 0.f ? 0.2f * a0 : a0;
            float a1 = ait.y + av.y; a1 = a1 < 0.f ? 0.2f * a1 : a1;
            e0 = __expf(a0);
            e1 = __expf(a1);
        }
        float den0 = e0, den1 = e1;
#pragma unroll
        for (int off = 32; off > 0; off >>= 1) {
            den0 += __shfl_xor(den0, off, 64);
            den1 += __shfl_xor(den1, off, 64);
        }
        float w0s = 0.5f * __fdividef(e0, den0 + 1e-16f);
        float w1s = 0.5f * __fdividef(e1, den1 + 1e-16f);
        float acc = 0.f;
        for (int j = 0; j < cnt; ++j) {
            int sj = __shfl(s_, j, 64);
            float w0 = __shfl(w0s, j, 64);
            float w1 = __shfl(w1s, j, 64);
            unsigned v = xtb[(size_t)sj * DH + lane];
            acc += w0 * __uint_as_float(v << 16) +
                   w1 * __uint_as_float(v & 0xffff0000u);
        }
        u = acc;
    } else {
        // ---- general two-pass path (rare: deg > 63) ----
        float acc0 = 0.f, acc1 = 0.f, den0 = 0.f, den1 = 0.f;
        for (int bs = 0; bs < cnt; bs += 64) {
            int idx = bs + lane;
            int s = t;
            float e0 = 0.f, e1 = 0.f;
            if (idx < cnt) {
                s = (idx < deg) ? csrc[beg + idx] : t;
                float2 av = aj2[s];
                float a0 = ait.x + av.x; a0 = a0 < 0.f ? 0.2f * a0 : a0;
                float a1 = ait.y + av.y; a1 = a1 < 0.f ? 0.2f * a1 : a1;
                e0 = __expf(a0);
                e1 = __expf(a1);
            }
            den0 += e0;
            den1 += e1;
            int m = min(64, cnt - bs);
            for (int j = 0; j < m; ++j) {
                int sj = __shfl(s, j, 64);
                float w0 = __shfl(e0, j, 64);
                float w1 = __shfl(e1, j, 64);
                unsigned v = xtb[(size_t)sj * DH + lane];
                acc0 += w0 * __uint_as_float(v << 16);
                acc1 += w1 * __uint_as_float(v & 0xffff0000u);
            }
        }
        den0 = wsum(den0);
        den1 = wsum(den1);
        u = 0.5f * (__fdividef(acc0, den0 + 1e-16f) +
                    __fdividef(acc1, den1 + 1e-16f));
    }
    // ---- HypAct with analytic norm tracking (2 reductions only) ----
    float Su = wsum(u * u);
    float nu = fmaxf(sqrtf(Su), 1e-15f);
    float the = ftanh(nu);                   // |e| after expmap0
    float e = the * __fdividef(u, nu);
    float nh = the;
    if (the > MAXN_F) { e *= MAXN_F / the; nh = MAXN_F; }   // proj
    float g = __fdividef(fatanh(fminf(nh, 1.f - 1e-7f)), fmaxf(nh, 1e-15f));
    float ht = g * e;
    ht = ht < 0.f ? 0.01f * ht : ht;          // leaky
    float St = wsum(ht * ht);
    float nt = fmaxf(sqrtf(St), 1e-15f);
    float to = ftanh(nt);                     // |o| after expmap0
    float o = to * __fdividef(ht, nt);
    if (to > MAXN_F) o *= MAXN_F / to;        // proj
    out[(size_t)t * DH + lane] = o;
}

extern "C" void kernel_launch(void* const* d_in, const int* in_sizes, int n_in,
                              void* d_out, int out_size, void* d_ws, size_t ws_size,
                              hipStream_t stream) {
    const float* x    = (const float*)d_in[0];
    const int*   eidx = (const int*)d_in[1];
    const float* W    = (const float*)d_in[2];
    const float* bias = (const float*)d_in[3];
    const float* atti = (const float*)d_in[4];
    const float* attj = (const float*)d_in[5];
    float* out = (float*)d_out;

    const int n = in_sizes[0] / DD;  // 100000
    const int E = in_sizes[1] / 2;   // 600000
    const size_t nf = (size_t)n;

    unsigned* xtb = (unsigned*)d_ws;            // n*64 dwords (bf16 pairs)
    float* ai  = (float*)(xtb + nf * DH);       // 2n
    float* aj  = ai + 2 * nf;                   // 2n
    int* deg    = (int*)(aj + 2 * nf);          // n
    int* rowptr = deg + nf;                     // n+1
    int* cursor = rowptr + nf + 1;              // n
    int* bsum   = cursor + nf;                  // 256
    int* csrc   = bsum + 256;                   // E

    const int nb = (n + 1023) / 1024;  // scan chunks (<=256)
    const int ngemm = (n + BM - 1) / BM;

    hipMemsetAsync(deg, 0, nf * sizeof(int), stream);
    gemm_node_k<<<ngemm, 256, 0, stream>>>(x, W, bias, atti, attj, eidx, deg,
                                           xtb, ai, aj, n, E);
    scan1_k<<<nb, 256, 0, stream>>>(deg, bsum, n);
    scan23_k<<<nb, 256, 0, stream>>>(deg, bsum, rowptr, cursor, n, E, nb);
    scatter_k<<<(E + 255) / 256, 256, 0, stream>>>(eidx, cursor, csrc, E);
    agg_fused_k<<<(n + 3) / 4, 256, 0, stream>>>(rowptr, csrc, ai, aj, xtb, out, n);
}

// Round 21
// 163.255 us; speedup vs baseline: 1.7984x; 1.0960x over previous
//
#include <hip/hip_runtime.h>
#include <hip/hip_bf16.h>
#include <math.h>

#define DD 128
#define DH 64
#define BM 64
#define MAXN_F (1.0f - 4e-3f)

typedef short s8v __attribute__((ext_vector_type(8)));   // 8 bf16 (4 VGPR)
typedef float f4v __attribute__((ext_vector_type(4)));   // MFMA accum

__device__ inline float wsum(float v) {
#pragma unroll
    for (int off = 32; off > 0; off >>= 1) v += __shfl_xor(v, off, 64);
    return v;
}
__device__ inline float gsum32(float v) {   // reduce within 32-lane group
#pragma unroll
    for (int off = 16; off > 0; off >>= 1) v += __shfl_xor(v, off, 64);
    return v;
}
__device__ inline int wsumi(int v) {
#pragma unroll
    for (int off = 32; off > 0; off >>= 1) v += __shfl_xor(v, off, 64);
    return v;
}
__device__ inline unsigned short f2bf16(float x) {
    unsigned u = __float_as_uint(x);
    u += 0x7fffu + ((u >> 16) & 1u);   // RNE
    return (unsigned short)(u >> 16);
}
__device__ inline unsigned packbf(float a, float b) {
    return (unsigned)f2bf16(a) | ((unsigned)f2bf16(b) << 16);
}
__device__ inline float fatanh(float z) {
    return 0.5f * __logf(__fdividef(1.f + z, 1.f - z));
}
__device__ inline float ftanh(float y) {
    y = fminf(y, 10.f);
    float e = __expf(2.f * y);
    return __fdividef(e - 1.f, e + 1.f);
}

// ---- one-shot: W fp32 -> bf16, pre-swizzled into MFMA chunk layout ------
__global__ __launch_bounds__(256) void wprep_k(const float* __restrict__ W,
                                               s8v* __restrict__ wbf) {
    int s = blockIdx.x * 256 + threadIdx.x;   // 0..2047
    if (s >= 2048) return;
    int row = s >> 4, ch = s & 15;
    const float4* W4 = reinterpret_cast<const float4*>(W);
    float4 f0 = W4[row * 32 + ch * 2];
    float4 f1 = W4[row * 32 + ch * 2 + 1];
    s8v hv;
    hv[0] = (short)f2bf16(f0.x); hv[1] = (short)f2bf16(f0.y);
    hv[2] = (short)f2bf16(f0.z); hv[3] = (short)f2bf16(f0.w);
    hv[4] = (short)f2bf16(f1.x); hv[5] = (short)f2bf16(f1.y);
    hv[6] = (short)f2bf16(f1.z); hv[7] = (short)f2bf16(f1.w);
    wbf[row * 16 + (ch ^ (row & 15))] = hv;
}

// ---- MFMA GEMM (mx = x@W^T, bf16 in / f32 acc) + analytic epilogue ------
__global__ __launch_bounds__(256) void gemm_node_k(
    const float* __restrict__ x, const s8v* __restrict__ wbf,
    const float* __restrict__ bias,
    const float* __restrict__ atti, const float* __restrict__ attj,
    const int* __restrict__ eidx, int* __restrict__ deg,
    unsigned* __restrict__ xtb, float* __restrict__ ai, float* __restrict__ aj,
    int n, int E) {
    __shared__ short wl[128 * 128];   // 32 KB bf16 W (pre-swizzled copy)
    __shared__ short xl[BM * 128];    // 16 KB bf16 x tile
    __shared__ float hbl[128];
    __shared__ float sxq[BM];
    const int row0 = blockIdx.x * BM;
    const int tid = threadIdx.x;
    const int wv = tid >> 6;
    const int lane = tid & 63;
    const int l15 = lane & 15;
    const int g = lane >> 4;
    const float4* x4 = reinterpret_cast<const float4*>(x);
    s8v* wl8 = reinterpret_cast<s8v*>(wl);
    s8v* xl8 = reinterpret_cast<s8v*>(xl);
    // ---- stage W: straight copy (already bf16 + swizzled) ----
#pragma unroll
    for (int i = 0; i < 8; ++i) {
        int s = tid + i * 256;            // 0..2047
        wl8[s] = wbf[s];
    }
    // ---- stage x tile + |x|^2 per row ----
#pragma unroll
    for (int i = 0; i < 4; ++i) {
        int s = tid + i * 256;            // 0..1023
        int r = s >> 4, ch = s & 15;
        int grow = row0 + r;
        float4 f0 = make_float4(0.f, 0.f, 0.f, 0.f), f1 = f0;
        if (grow < n) {
            f0 = x4[(size_t)grow * 32 + ch * 2];
            f1 = x4[(size_t)grow * 32 + ch * 2 + 1];
        }
        s8v hv;
        hv[0] = (short)f2bf16(f0.x); hv[1] = (short)f2bf16(f0.y);
        hv[2] = (short)f2bf16(f0.z); hv[3] = (short)f2bf16(f0.w);
        hv[4] = (short)f2bf16(f1.x); hv[5] = (short)f2bf16(f1.y);
        hv[6] = (short)f2bf16(f1.z); hv[7] = (short)f2bf16(f1.w);
        xl8[r * 16 + (ch ^ (r & 15))] = hv;
        float px = f0.x * f0.x + f0.y * f0.y + f0.z * f0.z + f0.w * f0.w +
                   f1.x * f1.x + f1.y * f1.y + f1.z * f1.z + f1.w * f1.w;
#pragma unroll
        for (int off = 8; off > 0; off >>= 1) px += __shfl_xor(px, off, 16);
        if ((tid & 15) == 0) sxq[r] = px;
    }
    // ---- per-wave bias/att pipeline (registers) ----
    float b0 = bias[lane], b1 = bias[64 + lane];
    float ai0 = atti[lane], ai1 = atti[64 + lane];
    float aj0 = attj[lane], aj1 = attj[64 + lane];
    float Sb = wsum(b0 * b0 + b1 * b1);
    float nb_ = fmaxf(sqrtf(Sb), 1e-15f);
    float th = tanhf(nb_) / nb_;
    float e0 = th * b0, e1 = th * b1;
    float Se = wsum(e0 * e0 + e1 * e1);
    float ne = fmaxf(sqrtf(Se), 1e-15f);
    if (ne > MAXN_F) { float sc = MAXN_F / ne; e0 *= sc; e1 *= sc; }
    float y2v = wsum(e0 * e0 + e1 * e1);
    float Yi0 = wsum(e0 * ai0), Yi1 = wsum(e1 * ai1);
    float Yj0 = wsum(e0 * aj0), Yj1 = wsum(e1 * aj1);
    if (tid < 64) { hbl[tid] = e0; hbl[64 + tid] = e1; }
    __syncthreads();
    // ---- per-lane col-vectors (col c = ct*16 + l15) ----
    float hbv[8], av[8], bv[8];
#pragma unroll
    for (int ct = 0; ct < 8; ++ct) {
        int c = ct * 16 + l15;
        hbv[ct] = hbl[c];
        av[ct] = atti[c];
        bv[ct] = attj[c];
    }
    // ---- MFMA: wave rows wv*16..+15, cols 0..127 ----
    f4v acc[8];
#pragma unroll
    for (int ct = 0; ct < 8; ++ct) acc[ct] = (f4v){0.f, 0.f, 0.f, 0.f};
#pragma unroll
    for (int kc = 0; kc < 4; ++kc) {
        s8v a = xl8[(wv * 16 + l15) * 16 + ((kc * 4 + g) ^ l15)];
#pragma unroll
        for (int ct = 0; ct < 8; ++ct) {
            s8v b = wl8[(ct * 16 + l15) * 16 + ((kc * 4 + g) ^ l15)];
            acc[ct] = __builtin_amdgcn_mfma_f32_16x16x32_bf16(a, b, acc[ct], 0, 0, 0);
        }
    }
    // ---- per-row scalar reductions (16-lane groups own a row's cols) ----
    float red[24];
#pragma unroll
    for (int reg = 0; reg < 4; ++reg) {
        float sm = 0.f, my = 0.f, d0 = 0.f, d1 = 0.f, f0 = 0.f, f1 = 0.f;
#pragma unroll
        for (int ct = 0; ct < 8; ++ct) {
            float v = acc[ct][reg];
            sm += v * v;
            my += v * hbv[ct];
            if (ct < 4) { d0 += v * av[ct]; f0 += v * bv[ct]; }
            else        { d1 += v * av[ct]; f1 += v * bv[ct]; }
        }
        red[reg * 6 + 0] = sm; red[reg * 6 + 1] = my;
        red[reg * 6 + 2] = d0; red[reg * 6 + 3] = d1;
        red[reg * 6 + 4] = f0; red[reg * 6 + 5] = f1;
    }
#pragma unroll
    for (int off = 8; off > 0; off >>= 1) {
#pragma unroll
        for (int j = 0; j < 24; ++j) red[j] += __shfl_xor(red[j], off, 16);
    }
    // ---- analytic chain + stores ----
#pragma unroll
    for (int reg = 0; reg < 4; ++reg) {
        int rr = wv * 16 + g * 4 + reg;
        int gr = row0 + rr;
        float Sx  = sxq[rr];
        float Sm  = red[reg * 6 + 0];
        float My  = red[reg * 6 + 1];
        float Di0 = red[reg * 6 + 2];
        float Di1 = red[reg * 6 + 3];
        float Dj0 = red[reg * 6 + 4];
        float Dj1 = red[reg * 6 + 5];
        float xn = fmaxf(sqrtf(Sx), 1e-15f);
        float mxn = fmaxf(sqrtf(Sm), 1e-15f);
        float art = fatanh(fminf(xn, 1.f - 1e-7f));
        float tn = ftanh(__fdividef(mxn, xn) * art);
        float rho = (Sm == 0.f) ? 0.f : __fdividef(tn, mxn);
        float pn = (Sm == 0.f) ? 0.f : tn;
        if (pn > MAXN_F) { rho *= MAXN_F / pn; pn = MAXN_F; }
        float X2 = pn * pn, XY = rho * My;
        float ca = 1.f + 2.f * XY + y2v;
        float cb = 1.f - X2;
        float dn = fmaxf(1.f + 2.f * XY + X2 * y2v, 1e-15f);
        float Sh = __fdividef(ca * ca * X2 + 2.f * ca * cb * XY + cb * cb * y2v,
                              dn * dn);
        float nraw = fmaxf(sqrtf(Sh), 1e-15f);
        float scp = 1.f, nh = nraw;
        if (nraw > MAXN_F) { scp = MAXN_F / nraw; nh = MAXN_F; }
        float gg = __fdividef(fatanh(fminf(nh, 1.f - 1e-7f)), nh);
        float gs = __fdividef(gg * scp, dn);
        float al = gs * ca * rho;
        float be = gs * cb;
        if (gr < n) {
#pragma unroll
            for (int ct = 0; ct < 4; ++ct) {
                xtb[(size_t)gr * DH + ct * 16 + l15] =
                    packbf(al * acc[ct][reg] + be * hbv[ct],
                           al * acc[ct + 4][reg] + be * hbv[ct + 4]);
            }
            if (l15 == 0) {
                reinterpret_cast<float2*>(ai)[gr] =
                    make_float2(al * Di0 + be * Yi0, al * Di1 + be * Yi1);
                reinterpret_cast<float2*>(aj)[gr] =
                    make_float2(al * Dj0 + be * Yj0, al * Dj1 + be * Yj1);
            }
        }
    }
    // ---- edge histogram tail ----
    {
        int perB = (E + gridDim.x - 1) / gridDim.x;
        int eb = blockIdx.x * perB;
        int ee = min(E, eb + perB);
        for (int e = eb + tid; e < ee; e += 256) atomicAdd(&deg[eidx[e]], 1);
    }
}

// ---------------- scan1: per-1024-chunk sums ----------------
__global__ __launch_bounds__(256) void scan1_k(const int* __restrict__ deg,
                                               int* __restrict__ bsum, int n) {
    int b = blockIdx.x, tid = threadIdx.x;
    int i0 = b * 1024 + tid * 4;
    int s = 0;
#pragma unroll
    for (int k = 0; k < 4; ++k)
        if (i0 + k < n) s += deg[i0 + k];
    s = wsumi(s);
    __shared__ int sm[4];
    if ((tid & 63) == 0) sm[tid >> 6] = s;
    __syncthreads();
    if (tid == 0) bsum[b] = sm[0] + sm[1] + sm[2] + sm[3];
}

// ---------------- scan23: top-level scan + rowptr/cursor ----------------
__global__ __launch_bounds__(256) void scan23_k(const int* __restrict__ deg,
                                                const int* __restrict__ bsum,
                                                int* __restrict__ rowptr,
                                                int* __restrict__ cursor,
                                                int n, int E, int nb) {
    int b = blockIdx.x, tid = threadIdx.x;
    __shared__ int sm2[256];
    int v = (tid < nb) ? bsum[tid] : 0;
    sm2[tid] = v;
    __syncthreads();
    for (int off = 1; off < 256; off <<= 1) {
        int u = (tid >= off) ? sm2[tid - off] : 0;
        __syncthreads();
        sm2[tid] += u;
        __syncthreads();
    }
    __shared__ int myoff;
    if (tid == 0) myoff = sm2[b] - bsum[b];
    __syncthreads();
    int i0 = b * 1024 + tid * 4;
    int d[4];
#pragma unroll
    for (int k = 0; k < 4; ++k) d[k] = (i0 + k < n) ? deg[i0 + k] : 0;
    int ts = d[0] + d[1] + d[2] + d[3];
    __shared__ int sm[256];
    sm[tid] = ts;
    __syncthreads();
    for (int off = 1; off < 256; off <<= 1) {
        int u = (tid >= off) ? sm[tid - off] : 0;
        __syncthreads();
        sm[tid] += u;
        __syncthreads();
    }
    int base = myoff + sm[tid] - ts;
    int pre = 0;
#pragma unroll
    for (int k = 0; k < 4; ++k) {
        if (i0 + k < n) {
            rowptr[i0 + k] = base + pre;
            cursor[i0 + k] = base + pre;
        }
        pre += d[k];
    }
    if (b == 0 && tid == 0) rowptr[n] = E;
}

// ---------------- CSR scatter ----------------
__global__ __launch_bounds__(256) void scatter_k(const int* __restrict__ eidx,
                                                 int* __restrict__ cursor,
                                                 int* __restrict__ csrc, int E) {
    int e = blockIdx.x * 256 + threadIdx.x;
    if (e >= E) return;
    int t = eidx[e], s = eidx[E + e];
    int pos = atomicAdd(&cursor[t], 1);
    csrc[pos] = s;
}

// ---- fused softmax + aggregation + HypAct: 2 nodes per wave -------------
// 32-lane groups; lane handles dims (2l, 2l+1) as float2. Fast path cnt<=32
// (max deg ~18 for this graph). No max-subtraction; analytic norm tracking.
__global__ __launch_bounds__(256) void agg_fused_k(
    const int* __restrict__ rowptr, const int* __restrict__ csrc,
    const float* __restrict__ ai, const float* __restrict__ aj,
    const unsigned* __restrict__ xtb, float* __restrict__ out, int n) {
    const int wid = (blockIdx.x * 256 + threadIdx.x) >> 6;
    const int grp = (threadIdx.x >> 5) & 1;
    const int l = threadIdx.x & 31;
    const int base = threadIdx.x & 32;     // shuffle base of my group
    int t0 = wid * 2 + grp;
    bool valid = (t0 < n);
    int t = valid ? t0 : (n - 1);
    const int beg = rowptr[t];
    const int deg = rowptr[t + 1] - beg;
    const int cnt = deg + 1;               // + self loop
    int cnt_o = __shfl_xor(cnt, 32, 64);
    int jmax = max(cnt, cnt_o);            // wave-uniform
    float2 ait = reinterpret_cast<const float2*>(ai)[t];
    const float2* aj2 = reinterpret_cast<const float2*>(aj);
    float ux, uy;
    if (jmax <= 32) {
        // ---- fast path ----
        int s_ = t;
        if (l < deg) s_ = csrc[beg + l];
        float e0 = 0.f, e1 = 0.f;
        if (l < cnt) {
            float2 av = aj2[s_];
            float a0 = ait.x + av.x; a0 = a0 < 0.f ? 0.2f * a0 : a0;
            float a1 = ait.y + av.y; a1 = a1 < 0.f ? 0.2f * a1 : a1;
            e0 = __expf(a0);
            e1 = __expf(a1);
        }
        float den0 = gsum32(e0), den1 = gsum32(e1);
        float w0s = 0.5f * __fdividef(e0, den0 + 1e-16f);
        float w1s = 0.5f * __fdividef(e1, den1 + 1e-16f);
        float ax = 0.f, ay = 0.f;
        for (int j = 0; j < jmax; ++j) {
            int sj = __shfl(s_, base + j, 64);
            float w0 = __shfl(w0s, base + j, 64);
            float w1 = __shfl(w1s, base + j, 64);
            if (j < cnt) {
                uint2 v = *reinterpret_cast<const uint2*>(
                    xtb + (size_t)sj * DH + 2 * l);
                ax += w0 * __uint_as_float(v.x << 16) +
                      w1 * __uint_as_float(v.x & 0xffff0000u);
                ay += w0 * __uint_as_float(v.y << 16) +
                      w1 * __uint_as_float(v.y & 0xffff0000u);
            }
        }
        ux = ax; uy = ay;
    } else {
        // ---- general path (deg > 31: essentially never for this graph) ----
        float a0x = 0.f, a0y = 0.f, a1x = 0.f, a1y = 0.f;
        float den0 = 0.f, den1 = 0.f;
        int bmax = (jmax + 31) & ~31;
        for (int bs = 0; bs < bmax; bs += 32) {
            int idx = bs + l;
            int s = t;
            float e0 = 0.f, e1 = 0.f;
            if (idx < cnt) {
                s = (idx < deg) ? csrc[beg + idx] : t;
                float2 av = aj2[s];
                float a0 = ait.x + av.x; a0 = a0 < 0.f ? 0.2f * a0 : a0;
                float a1 = ait.y + av.y; a1 = a1 < 0.f ? 0.2f * a1 : a1;
                e0 = __expf(a0);
                e1 = __expf(a1);
            }
            den0 += e0;
            den1 += e1;
            for (int j = 0; j < 32 && bs + j < jmax; ++j) {
                int sj = __shfl(s, base + j, 64);
                float w0 = __shfl(e0, base + j, 64);
                float w1 = __shfl(e1, base + j, 64);
                if (bs + j < cnt) {
                    uint2 v = *reinterpret_cast<const uint2*>(
                        xtb + (size_t)sj * DH + 2 * l);
                    float h0x = __uint_as_float(v.x << 16);
                    float h1x = __uint_as_float(v.x & 0xffff0000u);
                    float h0y = __uint_as_float(v.y << 16);
                    float h1y = __uint_as_float(v.y & 0xffff0000u);
                    a0x += w0 * h0x; a1x += w1 * h1x;
                    a0y += w0 * h0y; a1y += w1 * h1y;
                }
            }
        }
        den0 = gsum32(den0);
        den1 = gsum32(den1);
        ux = 0.5f * (__fdividef(a0x, den0 + 1e-16f) +
                     __fdividef(a1x, den1 + 1e-16f));
        uy = 0.5f * (__fdividef(a0y, den0 + 1e-16f) +
                     __fdividef(a1y, den1 + 1e-16f));
    }
    // ---- HypAct with analytic norm tracking (2 group reductions) ----
    float Su = gsum32(ux * ux + uy * uy);
    float nu = fmaxf(sqrtf(Su), 1e-15f);
    float the = ftanh(nu);                    // |e| after expmap0
    float iv = __fdividef(the, nu);
    float ex = iv * ux, ey = iv * uy;
    float nh = the;
    if (the > MAXN_F) {
        float sc = MAXN_F / the;
        ex *= sc; ey *= sc; nh = MAXN_F;
    }
    float g = __fdividef(fatanh(fminf(nh, 1.f - 1e-7f)), fmaxf(nh, 1e-15f));
    float htx = g * ex, hty = g * ey;
    htx = htx < 0.f ? 0.01f * htx : htx;       // leaky
    hty = hty < 0.f ? 0.01f * hty : hty;
    float St = gsum32(htx * htx + hty * hty);
    float nt = fmaxf(sqrtf(St), 1e-15f);
    float to = ftanh(nt);
    float ov = __fdividef(to, nt);
    float ox = ov * htx, oy = ov * hty;
    if (to > MAXN_F) { float sc = MAXN_F / to; ox *= sc; oy *= sc; }
    if (valid)
        reinterpret_cast<float2*>(out)[(size_t)t * 32 + l] = make_float2(ox, oy);
}

extern "C" void kernel_launch(void* const* d_in, const int* in_sizes, int n_in,
                              void* d_out, int out_size, void* d_ws, size_t ws_size,
                              hipStream_t stream) {
    const float* x    = (const float*)d_in[0];
    const int*   eidx = (const int*)d_in[1];
    const float* W    = (const float*)d_in[2];
    const float* bias = (const float*)d_in[3];
    const float* atti = (const float*)d_in[4];
    const float* attj = (const float*)d_in[5];
    float* out = (float*)d_out;

    const int n = in_sizes[0] / DD;  // 100000
    const int E = in_sizes[1] / 2;   // 600000
    const size_t nf = (size_t)n;

    unsigned* xtb = (unsigned*)d_ws;            // n*64 dwords (bf16 pairs)
    float* ai  = (float*)(xtb + nf * DH);       // 2n
    float* aj  = ai + 2 * nf;                   // 2n
    int* deg    = (int*)(aj + 2 * nf);          // n
    int* rowptr = deg + nf;                     // n+1
    int* cursor = rowptr + nf + 1;              // n
    int* bsum   = cursor + nf;                  // 256
    int* csrc   = bsum + 256;                   // E
    s8v* wbf    = (s8v*)(csrc + E + 16);        // 2048 chunks (32 KB)

    const int nb = (n + 1023) / 1024;  // scan chunks (<=256)
    const int ngemm = (n + BM - 1) / BM;
    const int npair = (n + 1) / 2;     // node pairs (2 per wave)

    hipMemsetAsync(deg, 0, nf * sizeof(int), stream);
    wprep_k<<<8, 256, 0, stream>>>(W, wbf);
    gemm_node_k<<<ngemm, 256, 0, stream>>>(x, wbf, bias, atti, attj, eidx, deg,
                                           xtb, ai, aj, n, E);
    scan1_k<<<nb, 256, 0, stream>>>(deg, bsum, n);
    scan23_k<<<nb, 256, 0, stream>>>(deg, bsum, rowptr, cursor, n, E, nb);
    scatter_k<<<(E + 255) / 256, 256, 0, stream>>>(eidx, cursor, csrc, E);
    agg_fused_k<<<(npair + 3) / 4, 256, 0, stream>>>(rowptr, csrc, ai, aj, xtb,
                                                     out, n);
}

// Round 22
// 161.391 us; speedup vs baseline: 1.8192x; 1.0116x over previous
//
#include <hip/hip_runtime.h>
#include <hip/hip_bf16.h>
#include <math.h>

#define DD 128
#define DH 64
#define BM 64
#define MAXN_F (1.0f - 4e-3f)

typedef short s8v __attribute__((ext_vector_type(8)));   // 8 bf16 (4 VGPR)
typedef float f4v __attribute__((ext_vector_type(4)));   // MFMA accum

__device__ inline float wsum(float v) {
#pragma unroll
    for (int off = 32; off > 0; off >>= 1) v += __shfl_xor(v, off, 64);
    return v;
}
__device__ inline float gsum32(float v) {   // reduce within 32-lane group
#pragma unroll
    for (int off = 16; off > 0; off >>= 1) v += __shfl_xor(v, off, 64);
    return v;
}
__device__ inline int wsumi(int v) {
#pragma unroll
    for (int off = 32; off > 0; off >>= 1) v += __shfl_xor(v, off, 64);
    return v;
}
__device__ inline unsigned short f2bf16(float x) {
    unsigned u = __float_as_uint(x);
    u += 0x7fffu + ((u >> 16) & 1u);   // RNE
    return (unsigned short)(u >> 16);
}
__device__ inline unsigned packbf(float a, float b) {
    return (unsigned)f2bf16(a) | ((unsigned)f2bf16(b) << 16);
}
__device__ inline float fatanh(float z) {
    return 0.5f * __logf(__fdividef(1.f + z, 1.f - z));
}
__device__ inline float ftanh(float y) {
    y = fminf(y, 10.f);
    float e = __expf(2.f * y);
    return __fdividef(e - 1.f, e + 1.f);
}

// ---- one-shot: W fp32 -> bf16 pre-swizzled; block 0 also computes the
// bias pipeline constants: hbg[128], cst={y2,Yi0,Yi1,Yj0,Yj1} -------------
__global__ __launch_bounds__(256) void wprep_k(
    const float* __restrict__ W, const float* __restrict__ bias,
    const float* __restrict__ atti, const float* __restrict__ attj,
    s8v* __restrict__ wbf, float* __restrict__ hbg, float* __restrict__ cst) {
    int s = blockIdx.x * 256 + threadIdx.x;   // 0..2047
    if (s < 2048) {
        int row = s >> 4, ch = s & 15;
        const float4* W4 = reinterpret_cast<const float4*>(W);
        float4 f0 = W4[row * 32 + ch * 2];
        float4 f1 = W4[row * 32 + ch * 2 + 1];
        s8v hv;
        hv[0] = (short)f2bf16(f0.x); hv[1] = (short)f2bf16(f0.y);
        hv[2] = (short)f2bf16(f0.z); hv[3] = (short)f2bf16(f0.w);
        hv[4] = (short)f2bf16(f1.x); hv[5] = (short)f2bf16(f1.y);
        hv[6] = (short)f2bf16(f1.z); hv[7] = (short)f2bf16(f1.w);
        wbf[row * 16 + (ch ^ (row & 15))] = hv;
    }
    if (blockIdx.x == 0) {
        __shared__ float red[2];
        int tid = threadIdx.x;
        bool act = tid < 128;
        float b  = act ? bias[tid] : 0.f;
        float av_ = act ? atti[tid] : 0.f;
        float bv_ = act ? attj[tid] : 0.f;
        float s1 = wsum(b * b);
        if (act && (tid & 63) == 0) red[tid >> 6] = s1;
        __syncthreads();
        float S = red[0] + red[1];
        __syncthreads();
        float nb_ = fmaxf(sqrtf(S), 1e-15f);
        float e = tanhf(nb_) * b / nb_;
        float s2 = wsum(e * e);
        if (act && (tid & 63) == 0) red[tid >> 6] = s2;
        __syncthreads();
        float ne = fmaxf(sqrtf(red[0] + red[1]), 1e-15f);
        __syncthreads();
        if (ne > MAXN_F) e *= MAXN_F / ne;
        if (act) hbg[tid] = e;
        float s3 = wsum(e * e);
        if (act && (tid & 63) == 0) red[tid >> 6] = s3;
        __syncthreads();
        if (tid == 0) cst[0] = red[0] + red[1];
        float di = wsum(e * av_);
        float dj = wsum(e * bv_);
        if (act && (tid & 63) == 0) {
            int h = tid >> 6;
            cst[1 + h] = di;   // Yi0 / Yi1
            cst[3 + h] = dj;   // Yj0 / Yj1
        }
    }
}

// ---- MFMA GEMM: x tile in LDS (17 KB), B-fragments from L2-hot wbf ------
__global__ __launch_bounds__(256) void gemm_node_k(
    const float* __restrict__ x, const s8v* __restrict__ wbf,
    const float* __restrict__ hbg, const float* __restrict__ cst,
    const float* __restrict__ atti, const float* __restrict__ attj,
    const int* __restrict__ eidx, int* __restrict__ deg,
    unsigned* __restrict__ xtb, float* __restrict__ ai, float* __restrict__ aj,
    int n, int E) {
    __shared__ short xl[BM * 128];    // 16 KB bf16 x tile
    __shared__ float sxq[BM];
    const int row0 = blockIdx.x * BM;
    const int tid = threadIdx.x;
    const int wv = tid >> 6;
    const int lane = tid & 63;
    const int l15 = lane & 15;
    const int g = lane >> 4;
    const float4* x4 = reinterpret_cast<const float4*>(x);
    s8v* xl8 = reinterpret_cast<s8v*>(xl);
    // ---- stage x tile + |x|^2 per row ----
#pragma unroll
    for (int i = 0; i < 4; ++i) {
        int s = tid + i * 256;            // 0..1023
        int r = s >> 4, ch = s & 15;
        int grow = row0 + r;
        float4 f0 = make_float4(0.f, 0.f, 0.f, 0.f), f1 = f0;
        if (grow < n) {
            f0 = x4[(size_t)grow * 32 + ch * 2];
            f1 = x4[(size_t)grow * 32 + ch * 2 + 1];
        }
        s8v hv;
        hv[0] = (short)f2bf16(f0.x); hv[1] = (short)f2bf16(f0.y);
        hv[2] = (short)f2bf16(f0.z); hv[3] = (short)f2bf16(f0.w);
        hv[4] = (short)f2bf16(f1.x); hv[5] = (short)f2bf16(f1.y);
        hv[6] = (short)f2bf16(f1.z); hv[7] = (short)f2bf16(f1.w);
        xl8[r * 16 + (ch ^ (r & 15))] = hv;
        float px = f0.x * f0.x + f0.y * f0.y + f0.z * f0.z + f0.w * f0.w +
                   f1.x * f1.x + f1.y * f1.y + f1.z * f1.z + f1.w * f1.w;
#pragma unroll
        for (int off = 8; off > 0; off >>= 1) px += __shfl_xor(px, off, 16);
        if ((tid & 15) == 0) sxq[r] = px;
    }
    // ---- constants (precomputed by wprep_k; all L2-hot) ----
    float y2v = cst[0];
    float Yi0 = cst[1], Yi1 = cst[2], Yj0 = cst[3], Yj1 = cst[4];
    float hbv[8], av[8], bv[8];
#pragma unroll
    for (int ct = 0; ct < 8; ++ct) {
        int c = ct * 16 + l15;
        hbv[ct] = hbg[c];
        av[ct] = atti[c];
        bv[ct] = attj[c];
    }
    __syncthreads();
    // ---- MFMA: wave rows wv*16..+15, cols 0..127; B from global wbf ----
    f4v acc[8];
#pragma unroll
    for (int ct = 0; ct < 8; ++ct) acc[ct] = (f4v){0.f, 0.f, 0.f, 0.f};
#pragma unroll
    for (int kc = 0; kc < 4; ++kc) {
        s8v a = xl8[(wv * 16 + l15) * 16 + ((kc * 4 + g) ^ l15)];
#pragma unroll
        for (int ct = 0; ct < 8; ++ct) {
            s8v b = wbf[(ct * 16 + l15) * 16 + ((kc * 4 + g) ^ l15)];
            acc[ct] = __builtin_amdgcn_mfma_f32_16x16x32_bf16(a, b, acc[ct], 0, 0, 0);
        }
    }
    // ---- per-row scalar reductions (16-lane groups own a row's cols) ----
    float red[24];
#pragma unroll
    for (int reg = 0; reg < 4; ++reg) {
        float sm = 0.f, my = 0.f, d0 = 0.f, d1 = 0.f, f0 = 0.f, f1 = 0.f;
#pragma unroll
        for (int ct = 0; ct < 8; ++ct) {
            float v = acc[ct][reg];
            sm += v * v;
            my += v * hbv[ct];
            if (ct < 4) { d0 += v * av[ct]; f0 += v * bv[ct]; }
            else        { d1 += v * av[ct]; f1 += v * bv[ct]; }
        }
        red[reg * 6 + 0] = sm; red[reg * 6 + 1] = my;
        red[reg * 6 + 2] = d0; red[reg * 6 + 3] = d1;
        red[reg * 6 + 4] = f0; red[reg * 6 + 5] = f1;
    }
#pragma unroll
    for (int off = 8; off > 0; off >>= 1) {
#pragma unroll
        for (int j = 0; j < 24; ++j) red[j] += __shfl_xor(red[j], off, 16);
    }
    // ---- analytic chain + stores ----
#pragma unroll
    for (int reg = 0; reg < 4; ++reg) {
        int rr = wv * 16 + g * 4 + reg;
        int gr = row0 + rr;
        float Sx  = sxq[rr];
        float Sm  = red[reg * 6 + 0];
        float My  = red[reg * 6 + 1];
        float Di0 = red[reg * 6 + 2];
        float Di1 = red[reg * 6 + 3];
        float Dj0 = red[reg * 6 + 4];
        float Dj1 = red[reg * 6 + 5];
        float xn = fmaxf(sqrtf(Sx), 1e-15f);
        float mxn = fmaxf(sqrtf(Sm), 1e-15f);
        float art = fatanh(fminf(xn, 1.f - 1e-7f));
        float tn = ftanh(__fdividef(mxn, xn) * art);
        float rho = (Sm == 0.f) ? 0.f : __fdividef(tn, mxn);
        float pn = (Sm == 0.f) ? 0.f : tn;
        if (pn > MAXN_F) { rho *= MAXN_F / pn; pn = MAXN_F; }
        float X2 = pn * pn, XY = rho * My;
        float ca = 1.f + 2.f * XY + y2v;
        float cb = 1.f - X2;
        float dn = fmaxf(1.f + 2.f * XY + X2 * y2v, 1e-15f);
        float Sh = __fdividef(ca * ca * X2 + 2.f * ca * cb * XY + cb * cb * y2v,
                              dn * dn);
        float nraw = fmaxf(sqrtf(Sh), 1e-15f);
        float scp = 1.f, nh = nraw;
        if (nraw > MAXN_F) { scp = MAXN_F / nraw; nh = MAXN_F; }
        float gg = __fdividef(fatanh(fminf(nh, 1.f - 1e-7f)), nh);
        float gs = __fdividef(gg * scp, dn);
        float al = gs * ca * rho;
        float be = gs * cb;
        if (gr < n) {
#pragma unroll
            for (int ct = 0; ct < 4; ++ct) {
                xtb[(size_t)gr * DH + ct * 16 + l15] =
                    packbf(al * acc[ct][reg] + be * hbv[ct],
                           al * acc[ct + 4][reg] + be * hbv[ct + 4]);
            }
            if (l15 == 0) {
                reinterpret_cast<float2*>(ai)[gr] =
                    make_float2(al * Di0 + be * Yi0, al * Di1 + be * Yi1);
                reinterpret_cast<float2*>(aj)[gr] =
                    make_float2(al * Dj0 + be * Yj0, al * Dj1 + be * Yj1);
            }
        }
    }
    // ---- edge histogram tail ----
    {
        int perB = (E + gridDim.x - 1) / gridDim.x;
        int eb = blockIdx.x * perB;
        int ee = min(E, eb + perB);
        for (int e = eb + tid; e < ee; e += 256) atomicAdd(&deg[eidx[e]], 1);
    }
}

// ---------------- scan1: per-1024-chunk sums ----------------
__global__ __launch_bounds__(256) void scan1_k(const int* __restrict__ deg,
                                               int* __restrict__ bsum, int n) {
    int b = blockIdx.x, tid = threadIdx.x;
    int i0 = b * 1024 + tid * 4;
    int s = 0;
#pragma unroll
    for (int k = 0; k < 4; ++k)
        if (i0 + k < n) s += deg[i0 + k];
    s = wsumi(s);
    __shared__ int sm[4];
    if ((tid & 63) == 0) sm[tid >> 6] = s;
    __syncthreads();
    if (tid == 0) bsum[b] = sm[0] + sm[1] + sm[2] + sm[3];
}

// ---------------- scan23: top-level scan + rowptr/cursor ----------------
__global__ __launch_bounds__(256) void scan23_k(const int* __restrict__ deg,
                                                const int* __restrict__ bsum,
                                                int* __restrict__ rowptr,
                                                int* __restrict__ cursor,
                                                int n, int E, int nb) {
    int b = blockIdx.x, tid = threadIdx.x;
    __shared__ int sm2[256];
    int v = (tid < nb) ? bsum[tid] : 0;
    sm2[tid] = v;
    __syncthreads();
    for (int off = 1; off < 256; off <<= 1) {
        int u = (tid >= off) ? sm2[tid - off] : 0;
        __syncthreads();
        sm2[tid] += u;
        __syncthreads();
    }
    __shared__ int myoff;
    if (tid == 0) myoff = sm2[b] - bsum[b];
    __syncthreads();
    int i0 = b * 1024 + tid * 4;
    int d[4];
#pragma unroll
    for (int k = 0; k < 4; ++k) d[k] = (i0 + k < n) ? deg[i0 + k] : 0;
    int ts = d[0] + d[1] + d[2] + d[3];
    __shared__ int sm[256];
    sm[tid] = ts;
    __syncthreads();
    for (int off = 1; off < 256; off <<= 1) {
        int u = (tid >= off) ? sm[tid - off] : 0;
        __syncthreads();
        sm[tid] += u;
        __syncthreads();
    }
    int base = myoff + sm[tid] - ts;
    int pre = 0;
#pragma unroll
    for (int k = 0; k < 4; ++k) {
        if (i0 + k < n) {
            rowptr[i0 + k] = base + pre;
            cursor[i0 + k] = base + pre;
        }
        pre += d[k];
    }
    if (b == 0 && tid == 0) rowptr[n] = E;
}

// ---------------- CSR scatter ----------------
__global__ __launch_bounds__(256) void scatter_k(const int* __restrict__ eidx,
                                                 int* __restrict__ cursor,
                                                 int* __restrict__ csrc, int E) {
    int e = blockIdx.x * 256 + threadIdx.x;
    if (e >= E) return;
    int t = eidx[e], s = eidx[E + e];
    int pos = atomicAdd(&cursor[t], 1);
    csrc[pos] = s;
}

// ---- fused softmax + aggregation + HypAct: 2 nodes per wave -------------
__global__ __launch_bounds__(256) void agg_fused_k(
    const int* __restrict__ rowptr, const int* __restrict__ csrc,
    const float* __restrict__ ai, const float* __restrict__ aj,
    const unsigned* __restrict__ xtb, float* __restrict__ out, int n) {
    const int wid = (blockIdx.x * 256 + threadIdx.x) >> 6;
    const int grp = (threadIdx.x >> 5) & 1;
    const int l = threadIdx.x & 31;
    const int base = threadIdx.x & 32;     // shuffle base of my group
    int t0 = wid * 2 + grp;
    bool valid = (t0 < n);
    int t = valid ? t0 : (n - 1);
    const int beg = rowptr[t];
    const int deg = rowptr[t + 1] - beg;
    const int cnt = deg + 1;               // + self loop
    int cnt_o = __shfl_xor(cnt, 32, 64);
    int jmax = max(cnt, cnt_o);            // wave-uniform
    float2 ait = reinterpret_cast<const float2*>(ai)[t];
    const float2* aj2 = reinterpret_cast<const float2*>(aj);
    float ux, uy;
    if (jmax <= 32) {
        // ---- fast path ----
        int s_ = t;
        if (l < deg) s_ = csrc[beg + l];
        float e0 = 0.f, e1 = 0.f;
        if (l < cnt) {
            float2 av = aj2[s_];
            float a0 = ait.x + av.x; a0 = a0 < 0.f ? 0.2f * a0 : a0;
            float a1 = ait.y + av.y; a1 = a1 < 0.f ? 0.2f * a1 : a1;
            e0 = __expf(a0);
            e1 = __expf(a1);
        }
        float den0 = gsum32(e0), den1 = gsum32(e1);
        float w0s = 0.5f * __fdividef(e0, den0 + 1e-16f);
        float w1s = 0.5f * __fdividef(e1, den1 + 1e-16f);
        float ax = 0.f, ay = 0.f;
        for (int j = 0; j < jmax; ++j) {
            int sj = __shfl(s_, base + j, 64);
            float w0 = __shfl(w0s, base + j, 64);
            float w1 = __shfl(w1s, base + j, 64);
            if (j < cnt) {
                uint2 v = *reinterpret_cast<const uint2*>(
                    xtb + (size_t)sj * DH + 2 * l);
                ax += w0 * __uint_as_float(v.x << 16) +
                      w1 * __uint_as_float(v.x & 0xffff0000u);
                ay += w0 * __uint_as_float(v.y << 16) +
                      w1 * __uint_as_float(v.y & 0xffff0000u);
            }
        }
        ux = ax; uy = ay;
    } else {
        // ---- general path (deg > 31: essentially never for this graph) ----
        float a0x = 0.f, a0y = 0.f, a1x = 0.f, a1y = 0.f;
        float den0 = 0.f, den1 = 0.f;
        int bmax = (jmax + 31) & ~31;
        for (int bs = 0; bs < bmax; bs += 32) {
            int idx = bs + l;
            int s = t;
            float e0 = 0.f, e1 = 0.f;
            if (idx < cnt) {
                s = (idx < deg) ? csrc[beg + idx] : t;
                float2 av = aj2[s];
                float a0 = ait.x + av.x; a0 = a0 < 0.f ? 0.2f * a0 : a0;
                float a1 = ait.y + av.y; a1 = a1 < 0.f ? 0.2f * a1 : a1;
                e0 = __expf(a0);
                e1 = __expf(a1);
            }
            den0 += e0;
            den1 += e1;
            for (int j = 0; j < 32 && bs + j < jmax; ++j) {
                int sj = __shfl(s, base + j, 64);
                float w0 = __shfl(e0, base + j, 64);
                float w1 = __shfl(e1, base + j, 64);
                if (bs + j < cnt) {
                    uint2 v = *reinterpret_cast<const uint2*>(
                        xtb + (size_t)sj * DH + 2 * l);
                    float h0x = __uint_as_float(v.x << 16);
                    float h1x = __uint_as_float(v.x & 0xffff0000u);
                    float h0y = __uint_as_float(v.y << 16);
                    float h1y = __uint_as_float(v.y & 0xffff0000u);
                    a0x += w0 * h0x; a1x += w1 * h1x;
                    a0y += w0 * h0y; a1y += w1 * h1y;
                }
            }
        }
        den0 = gsum32(den0);
        den1 = gsum32(den1);
        ux = 0.5f * (__fdividef(a0x, den0 + 1e-16f) +
                     __fdividef(a1x, den1 + 1e-16f));
        uy = 0.5f * (__fdividef(a0y, den0 + 1e-16f) +
                     __fdividef(a1y, den1 + 1e-16f));
    }
    // ---- HypAct with analytic norm tracking (2 group reductions) ----
    float Su = gsum32(ux * ux + uy * uy);
    float nu = fmaxf(sqrtf(Su), 1e-15f);
    float the = ftanh(nu);                    // |e| after expmap0
    float iv = __fdividef(the, nu);
    float ex = iv * ux, ey = iv * uy;
    float nh = the;
    if (the > MAXN_F) {
        float sc = MAXN_F / the;
        ex *= sc; ey *= sc; nh = MAXN_F;
    }
    float g = __fdividef(fatanh(fminf(nh, 1.f - 1e-7f)), fmaxf(nh, 1e-15f));
    float htx = g * ex, hty = g * ey;
    htx = htx < 0.f ? 0.01f * htx : htx;       // leaky
    hty = hty < 0.f ? 0.01f * hty : hty;
    float St = gsum32(htx * htx + hty * hty);
    float nt = fmaxf(sqrtf(St), 1e-15f);
    float to = ftanh(nt);
    float ov = __fdividef(to, nt);
    float ox = ov * htx, oy = ov * hty;
    if (to > MAXN_F) { float sc = MAXN_F / to; ox *= sc; oy *= sc; }
    if (valid)
        reinterpret_cast<float2*>(out)[(size_t)t * 32 + l] = make_float2(ox, oy);
}

extern "C" void kernel_launch(void* const* d_in, const int* in_sizes, int n_in,
                              void* d_out, int out_size, void* d_ws, size_t ws_size,
                              hipStream_t stream) {
    const float* x    = (const float*)d_in[0];
    const int*   eidx = (const int*)d_in[1];
    const float* W    = (const float*)d_in[2];
    const float* bias = (const float*)d_in[3];
    const float* atti = (const float*)d_in[4];
    const float* attj = (const float*)d_in[5];
    float* out = (float*)d_out;

    const int n = in_sizes[0] / DD;  // 100000
    const int E = in_sizes[1] / 2;   // 600000
    const size_t nf = (size_t)n;

    unsigned* xtb = (unsigned*)d_ws;            // n*64 dwords (bf16 pairs)
    float* ai  = (float*)(xtb + nf * DH);       // 2n
    float* aj  = ai + 2 * nf;                   // 2n
    int* deg    = (int*)(aj + 2 * nf);          // n
    int* rowptr = deg + nf;                     // n+1
    int* cursor = rowptr + nf + 1;              // n
    int* bsum   = cursor + nf;                  // 256
    int* csrc   = bsum + 256;                   // E
    s8v* wbf    = (s8v*)(csrc + E + 16);        // 2048 chunks (32 KB)
    float* hbg  = (float*)(wbf + 2048);         // 128
    float* cst  = hbg + 128;                    // 5

    const int nb = (n + 1023) / 1024;  // scan chunks (<=256)
    const int ngemm = (n + BM - 1) / BM;
    const int npair = (n + 1) / 2;     // node pairs (2 per wave)

    hipMemsetAsync(deg, 0, nf * sizeof(int), stream);
    wprep_k<<<8, 256, 0, stream>>>(W, bias, atti, attj, wbf, hbg, cst);
    gemm_node_k<<<ngemm, 256, 0, stream>>>(x, wbf, hbg, cst, atti, attj, eidx,
                                           deg, xtb, ai, aj, n, E);
    scan1_k<<<nb, 256, 0, stream>>>(deg, bsum, n);
    scan23_k<<<nb, 256, 0, stream>>>(deg, bsum, rowptr, cursor, n, E, nb);
    scatter_k<<<(E + 255) / 256, 256, 0, stream>>>(eidx, cursor, csrc, E);
    agg_fused_k<<<(npair + 3) / 4, 256, 0, stream>>>(rowptr, csrc, ai, aj, xtb,
                                                     out, n);
}

// Round 23
// 140.035 us; speedup vs baseline: 2.0966x; 1.1525x over previous
//
#include <hip/hip_runtime.h>
#include <hip/hip_bf16.h>
#include <math.h>

#define DD 128
#define DH 64
#define BM 128
#define NTHR_G 512
#define MAXN_F (1.0f - 4e-3f)

typedef short s8v __attribute__((ext_vector_type(8)));   // 8 bf16 (4 VGPR)
typedef float f4v __attribute__((ext_vector_type(4)));   // MFMA accum

__device__ inline float wsum(float v) {
#pragma unroll
    for (int off = 32; off > 0; off >>= 1) v += __shfl_xor(v, off, 64);
    return v;
}
__device__ inline float gsum32(float v) {   // reduce within 32-lane group
#pragma unroll
    for (int off = 16; off > 0; off >>= 1) v += __shfl_xor(v, off, 64);
    return v;
}
__device__ inline int wsumi(int v) {
#pragma unroll
    for (int off = 32; off > 0; off >>= 1) v += __shfl_xor(v, off, 64);
    return v;
}
__device__ inline unsigned short f2bf16(float x) {
    unsigned u = __float_as_uint(x);
    u += 0x7fffu + ((u >> 16) & 1u);   // RNE
    return (unsigned short)(u >> 16);
}
__device__ inline unsigned packbf(float a, float b) {
    return (unsigned)f2bf16(a) | ((unsigned)f2bf16(b) << 16);
}
__device__ inline float fatanh(float z) {
    return 0.5f * __logf(__fdividef(1.f + z, 1.f - z));
}
__device__ inline float ftanh(float y) {
    y = fminf(y, 10.f);
    float e = __expf(2.f * y);
    return __fdividef(e - 1.f, e + 1.f);
}

// ---- one-shot: W fp32->bf16 pre-swizzled; zero deg; block 0: bias consts --
__global__ __launch_bounds__(256) void wprep_k(
    const float* __restrict__ W, const float* __restrict__ bias,
    const float* __restrict__ atti, const float* __restrict__ attj,
    s8v* __restrict__ wbf, float* __restrict__ hbg, float* __restrict__ cst,
    int* __restrict__ deg, int n) {
    int s = blockIdx.x * 256 + threadIdx.x;
    if (s < 2048) {
        int row = s >> 4, ch = s & 15;
        const float4* W4 = reinterpret_cast<const float4*>(W);
        float4 f0 = W4[row * 32 + ch * 2];
        float4 f1 = W4[row * 32 + ch * 2 + 1];
        s8v hv;
        hv[0] = (short)f2bf16(f0.x); hv[1] = (short)f2bf16(f0.y);
        hv[2] = (short)f2bf16(f0.z); hv[3] = (short)f2bf16(f0.w);
        hv[4] = (short)f2bf16(f1.x); hv[5] = (short)f2bf16(f1.y);
        hv[6] = (short)f2bf16(f1.z); hv[7] = (short)f2bf16(f1.w);
        wbf[row * 16 + (ch ^ (row & 15))] = hv;
    }
    // zero deg (grid-stride over all blocks)
    for (int i = s; i < n; i += gridDim.x * 256) deg[i] = 0;
    if (blockIdx.x == 0) {
        __shared__ float red[2];
        int tid = threadIdx.x;
        bool act = tid < 128;
        float b  = act ? bias[tid] : 0.f;
        float av_ = act ? atti[tid] : 0.f;
        float bv_ = act ? attj[tid] : 0.f;
        float s1 = wsum(b * b);
        if (act && (tid & 63) == 0) red[tid >> 6] = s1;
        __syncthreads();
        float S = red[0] + red[1];
        __syncthreads();
        float nb_ = fmaxf(sqrtf(S), 1e-15f);
        float e = tanhf(nb_) * b / nb_;
        float s2 = wsum(e * e);
        if (act && (tid & 63) == 0) red[tid >> 6] = s2;
        __syncthreads();
        float ne = fmaxf(sqrtf(red[0] + red[1]), 1e-15f);
        __syncthreads();
        if (ne > MAXN_F) e *= MAXN_F / ne;
        if (act) hbg[tid] = e;
        float s3 = wsum(e * e);
        if (act && (tid & 63) == 0) red[tid >> 6] = s3;
        __syncthreads();
        if (tid == 0) cst[0] = red[0] + red[1];
        float di = wsum(e * av_);
        float dj = wsum(e * bv_);
        if (act && (tid & 63) == 0) {
            int h = tid >> 6;
            cst[1 + h] = di;   // Yi0 / Yi1
            cst[3 + h] = dj;   // Yj0 / Yj1
        }
    }
}

// ---- MFMA GEMM: BM=128 rows, 512 thr = 8 waves; x tile in LDS (33 KB),
// B-fragments from L2-hot wbf -------------------------------------------
__global__ __launch_bounds__(NTHR_G) void gemm_node_k(
    const float* __restrict__ x, const s8v* __restrict__ wbf,
    const float* __restrict__ hbg, const float* __restrict__ cst,
    const float* __restrict__ atti, const float* __restrict__ attj,
    const int* __restrict__ eidx, int* __restrict__ deg,
    unsigned* __restrict__ xtb, float* __restrict__ ai, float* __restrict__ aj,
    int n, int E) {
    __shared__ short xl[BM * 128];    // 32 KB bf16 x tile
    __shared__ float sxq[BM];
    const int row0 = blockIdx.x * BM;
    const int tid = threadIdx.x;
    const int wv = tid >> 6;          // 0..7
    const int lane = tid & 63;
    const int l15 = lane & 15;
    const int g = lane >> 4;
    const float4* x4 = reinterpret_cast<const float4*>(x);
    s8v* xl8 = reinterpret_cast<s8v*>(xl);
    // ---- stage x tile + |x|^2 per row ----
#pragma unroll
    for (int i = 0; i < 4; ++i) {
        int s = tid + i * NTHR_G;         // 0..2047
        int r = s >> 4, ch = s & 15;
        int grow = row0 + r;
        float4 f0 = make_float4(0.f, 0.f, 0.f, 0.f), f1 = f0;
        if (grow < n) {
            f0 = x4[(size_t)grow * 32 + ch * 2];
            f1 = x4[(size_t)grow * 32 + ch * 2 + 1];
        }
        s8v hv;
        hv[0] = (short)f2bf16(f0.x); hv[1] = (short)f2bf16(f0.y);
        hv[2] = (short)f2bf16(f0.z); hv[3] = (short)f2bf16(f0.w);
        hv[4] = (short)f2bf16(f1.x); hv[5] = (short)f2bf16(f1.y);
        hv[6] = (short)f2bf16(f1.z); hv[7] = (short)f2bf16(f1.w);
        xl8[r * 16 + (ch ^ (r & 15))] = hv;
        float px = f0.x * f0.x + f0.y * f0.y + f0.z * f0.z + f0.w * f0.w +
                   f1.x * f1.x + f1.y * f1.y + f1.z * f1.z + f1.w * f1.w;
#pragma unroll
        for (int off = 8; off > 0; off >>= 1) px += __shfl_xor(px, off, 16);
        if ((tid & 15) == 0) sxq[r] = px;
    }
    // ---- constants (precomputed; L2-hot) ----
    float y2v = cst[0];
    float Yi0 = cst[1], Yi1 = cst[2], Yj0 = cst[3], Yj1 = cst[4];
    float hbv[8], av[8], bv[8];
#pragma unroll
    for (int ct = 0; ct < 8; ++ct) {
        int c = ct * 16 + l15;
        hbv[ct] = hbg[c];
        av[ct] = atti[c];
        bv[ct] = attj[c];
    }
    __syncthreads();
    // ---- MFMA: wave rows wv*16..+15, cols 0..127; B from global wbf ----
    f4v acc[8];
#pragma unroll
    for (int ct = 0; ct < 8; ++ct) acc[ct] = (f4v){0.f, 0.f, 0.f, 0.f};
#pragma unroll
    for (int kc = 0; kc < 4; ++kc) {
        s8v a = xl8[(wv * 16 + l15) * 16 + ((kc * 4 + g) ^ l15)];
#pragma unroll
        for (int ct = 0; ct < 8; ++ct) {
            s8v b = wbf[(ct * 16 + l15) * 16 + ((kc * 4 + g) ^ l15)];
            acc[ct] = __builtin_amdgcn_mfma_f32_16x16x32_bf16(a, b, acc[ct], 0, 0, 0);
        }
    }
    // ---- per-row scalar reductions (16-lane groups own a row's cols) ----
    float red[24];
#pragma unroll
    for (int reg = 0; reg < 4; ++reg) {
        float sm = 0.f, my = 0.f, d0 = 0.f, d1 = 0.f, f0 = 0.f, f1 = 0.f;
#pragma unroll
        for (int ct = 0; ct < 8; ++ct) {
            float v = acc[ct][reg];
            sm += v * v;
            my += v * hbv[ct];
            if (ct < 4) { d0 += v * av[ct]; f0 += v * bv[ct]; }
            else        { d1 += v * av[ct]; f1 += v * bv[ct]; }
        }
        red[reg * 6 + 0] = sm; red[reg * 6 + 1] = my;
        red[reg * 6 + 2] = d0; red[reg * 6 + 3] = d1;
        red[reg * 6 + 4] = f0; red[reg * 6 + 5] = f1;
    }
#pragma unroll
    for (int off = 8; off > 0; off >>= 1) {
#pragma unroll
        for (int j = 0; j < 24; ++j) red[j] += __shfl_xor(red[j], off, 16);
    }
    // ---- analytic chain + stores ----
#pragma unroll
    for (int reg = 0; reg < 4; ++reg) {
        int rr = wv * 16 + g * 4 + reg;
        int gr = row0 + rr;
        float Sx  = sxq[rr];
        float Sm  = red[reg * 6 + 0];
        float My  = red[reg * 6 + 1];
        float Di0 = red[reg * 6 + 2];
        float Di1 = red[reg * 6 + 3];
        float Dj0 = red[reg * 6 + 4];
        float Dj1 = red[reg * 6 + 5];
        float xn = fmaxf(sqrtf(Sx), 1e-15f);
        float mxn = fmaxf(sqrtf(Sm), 1e-15f);
        float art = fatanh(fminf(xn, 1.f - 1e-7f));
        float tn = ftanh(__fdividef(mxn, xn) * art);
        float rho = (Sm == 0.f) ? 0.f : __fdividef(tn, mxn);
        float pn = (Sm == 0.f) ? 0.f : tn;
        if (pn > MAXN_F) { rho *= MAXN_F / pn; pn = MAXN_F; }
        float X2 = pn * pn, XY = rho * My;
        float ca = 1.f + 2.f * XY + y2v;
        float cb = 1.f - X2;
        float dn = fmaxf(1.f + 2.f * XY + X2 * y2v, 1e-15f);
        float Sh = __fdividef(ca * ca * X2 + 2.f * ca * cb * XY + cb * cb * y2v,
                              dn * dn);
        float nraw = fmaxf(sqrtf(Sh), 1e-15f);
        float scp = 1.f, nh = nraw;
        if (nraw > MAXN_F) { scp = MAXN_F / nraw; nh = MAXN_F; }
        float gg = __fdividef(fatanh(fminf(nh, 1.f - 1e-7f)), nh);
        float gs = __fdividef(gg * scp, dn);
        float al = gs * ca * rho;
        float be = gs * cb;
        if (gr < n) {
#pragma unroll
            for (int ct = 0; ct < 4; ++ct) {
                xtb[(size_t)gr * DH + ct * 16 + l15] =
                    packbf(al * acc[ct][reg] + be * hbv[ct],
                           al * acc[ct + 4][reg] + be * hbv[ct + 4]);
            }
            if (l15 == 0) {
                reinterpret_cast<float2*>(ai)[gr] =
                    make_float2(al * Di0 + be * Yi0, al * Di1 + be * Yi1);
                reinterpret_cast<float2*>(aj)[gr] =
                    make_float2(al * Dj0 + be * Yj0, al * Dj1 + be * Yj1);
            }
        }
    }
    // ---- edge histogram tail ----
    {
        int perB = (E + gridDim.x - 1) / gridDim.x;
        int eb = blockIdx.x * perB;
        int ee = min(E, eb + perB);
        for (int e = eb + tid; e < ee; e += NTHR_G) atomicAdd(&deg[eidx[e]], 1);
    }
}

// ---------------- scan1: per-1024-chunk sums ----------------
__global__ __launch_bounds__(256) void scan1_k(const int* __restrict__ deg,
                                               int* __restrict__ bsum, int n) {
    int b = blockIdx.x, tid = threadIdx.x;
    int i0 = b * 1024 + tid * 4;
    int s = 0;
#pragma unroll
    for (int k = 0; k < 4; ++k)
        if (i0 + k < n) s += deg[i0 + k];
    s = wsumi(s);
    __shared__ int sm[4];
    if ((tid & 63) == 0) sm[tid >> 6] = s;
    __syncthreads();
    if (tid == 0) bsum[b] = sm[0] + sm[1] + sm[2] + sm[3];
}

// ---------------- scan23: top-level scan + rowptr/cursor ----------------
__global__ __launch_bounds__(256) void scan23_k(const int* __restrict__ deg,
                                                const int* __restrict__ bsum,
                                                int* __restrict__ rowptr,
                                                int* __restrict__ cursor,
                                                int n, int E, int nb) {
    int b = blockIdx.x, tid = threadIdx.x;
    __shared__ int sm2[256];
    int v = (tid < nb) ? bsum[tid] : 0;
    sm2[tid] = v;
    __syncthreads();
    for (int off = 1; off < 256; off <<= 1) {
        int u = (tid >= off) ? sm2[tid - off] : 0;
        __syncthreads();
        sm2[tid] += u;
        __syncthreads();
    }
    __shared__ int myoff;
    if (tid == 0) myoff = sm2[b] - bsum[b];
    __syncthreads();
    int i0 = b * 1024 + tid * 4;
    int d[4];
#pragma unroll
    for (int k = 0; k < 4; ++k) d[k] = (i0 + k < n) ? deg[i0 + k] : 0;
    int ts = d[0] + d[1] + d[2] + d[3];
    __shared__ int sm[256];
    sm[tid] = ts;
    __syncthreads();
    for (int off = 1; off < 256; off <<= 1) {
        int u = (tid >= off) ? sm[tid - off] : 0;
        __syncthreads();
        sm[tid] += u;
        __syncthreads();
    }
    int base = myoff + sm[tid] - ts;
    int pre = 0;
#pragma unroll
    for (int k = 0; k < 4; ++k) {
        if (i0 + k < n) {
            rowptr[i0 + k] = base + pre;
            cursor[i0 + k] = base + pre;
        }
        pre += d[k];
    }
    if (b == 0 && tid == 0) rowptr[n] = E;
}

// ---------------- CSR scatter ----------------
__global__ __launch_bounds__(256) void scatter_k(const int* __restrict__ eidx,
                                                 int* __restrict__ cursor,
                                                 int* __restrict__ csrc, int E) {
    int e = blockIdx.x * 256 + threadIdx.x;
    if (e >= E) return;
    int t = eidx[e], s = eidx[E + e];
    int pos = atomicAdd(&cursor[t], 1);
    csrc[pos] = s;
}

// ---- fused softmax + aggregation + HypAct: 2 nodes/wave, branch-free ----
__global__ __launch_bounds__(256) void agg_fused_k(
    const int* __restrict__ rowptr, const int* __restrict__ csrc,
    const float* __restrict__ ai, const float* __restrict__ aj,
    const unsigned* __restrict__ xtb, float* __restrict__ out, int n) {
    const int wid = (blockIdx.x * 256 + threadIdx.x) >> 6;
    const int grp = (threadIdx.x >> 5) & 1;
    const int l = threadIdx.x & 31;
    const int base = threadIdx.x & 32;     // shuffle base of my group
    int t0 = wid * 2 + grp;
    bool valid = (t0 < n);
    int t = valid ? t0 : (n - 1);
    const int beg = rowptr[t];
    const int deg = rowptr[t + 1] - beg;
    const int cnt = deg + 1;               // + self loop
    int cnt_o = __shfl_xor(cnt, 32, 64);
    int jmax = max(cnt, cnt_o);            // wave-uniform
    float2 ait = reinterpret_cast<const float2*>(ai)[t];
    const float2* aj2 = reinterpret_cast<const float2*>(aj);
    float ux, uy;
    if (jmax <= 32) {
        // ---- fast path: lanes >= cnt hold s_=t, weight 0 -> no guards ----
        int s_ = t;
        if (l < deg) s_ = csrc[beg + l];
        float e0 = 0.f, e1 = 0.f;
        if (l < cnt) {
            float2 av = aj2[s_];
            float a0 = ait.x + av.x; a0 = a0 < 0.f ? 0.2f * a0 : a0;
            float a1 = ait.y + av.y; a1 = a1 < 0.f ? 0.2f * a1 : a1;
            e0 = __expf(a0);
            e1 = __expf(a1);
        }
        float den0 = gsum32(e0), den1 = gsum32(e1);
        float w0s = 0.5f * __fdividef(e0, den0 + 1e-16f);
        float w1s = 0.5f * __fdividef(e1, den1 + 1e-16f);
        float ax = 0.f, ay = 0.f;
        int j = 0;
        for (; j + 1 < jmax; j += 2) {
            int sA = __shfl(s_, base + j, 64);
            float wA0 = __shfl(w0s, base + j, 64);
            float wA1 = __shfl(w1s, base + j, 64);
            int sB = __shfl(s_, base + j + 1, 64);
            float wB0 = __shfl(w0s, base + j + 1, 64);
            float wB1 = __shfl(w1s, base + j + 1, 64);
            uint2 vA = *reinterpret_cast<const uint2*>(
                xtb + (size_t)sA * DH + 2 * l);
            uint2 vB = *reinterpret_cast<const uint2*>(
                xtb + (size_t)sB * DH + 2 * l);
            ax += wA0 * __uint_as_float(vA.x << 16) +
                  wA1 * __uint_as_float(vA.x & 0xffff0000u) +
                  wB0 * __uint_as_float(vB.x << 16) +
                  wB1 * __uint_as_float(vB.x & 0xffff0000u);
            ay += wA0 * __uint_as_float(vA.y << 16) +
                  wA1 * __uint_as_float(vA.y & 0xffff0000u) +
                  wB0 * __uint_as_float(vB.y << 16) +
                  wB1 * __uint_as_float(vB.y & 0xffff0000u);
        }
        if (j < jmax) {
            int sA = __shfl(s_, base + j, 64);
            float wA0 = __shfl(w0s, base + j, 64);
            float wA1 = __shfl(w1s, base + j, 64);
            uint2 vA = *reinterpret_cast<const uint2*>(
                xtb + (size_t)sA * DH + 2 * l);
            ax += wA0 * __uint_as_float(vA.x << 16) +
                  wA1 * __uint_as_float(vA.x & 0xffff0000u);
            ay += wA0 * __uint_as_float(vA.y << 16) +
                  wA1 * __uint_as_float(vA.y & 0xffff0000u);
        }
        ux = ax; uy = ay;
    } else {
        // ---- general path (deg > 31: essentially never for this graph) ----
        float a0x = 0.f, a0y = 0.f, a1x = 0.f, a1y = 0.f;
        float den0 = 0.f, den1 = 0.f;
        int bmax = (jmax + 31) & ~31;
        for (int bs = 0; bs < bmax; bs += 32) {
            int idx = bs + l;
            int s = t;
            float e0 = 0.f, e1 = 0.f;
            if (idx < cnt) {
                s = (idx < deg) ? csrc[beg + idx] : t;
                float2 av = aj2[s];
                float a0 = ait.x + av.x; a0 = a0 < 0.f ? 0.2f * a0 : a0;
                float a1 = ait.y + av.y; a1 = a1 < 0.f ? 0.2f * a1 : a1;
                e0 = __expf(a0);
                e1 = __expf(a1);
            }
            den0 += e0;
            den1 += e1;
            for (int j = 0; j < 32 && bs + j < jmax; ++j) {
                int sj = __shfl(s, base + j, 64);
                float w0 = __shfl(e0, base + j, 64);
                float w1 = __shfl(e1, base + j, 64);
                if (bs + j < cnt) {
                    uint2 v = *reinterpret_cast<const uint2*>(
                        xtb + (size_t)sj * DH + 2 * l);
                    float h0x = __uint_as_float(v.x << 16);
                    float h1x = __uint_as_float(v.x & 0xffff0000u);
                    float h0y = __uint_as_float(v.y << 16);
                    float h1y = __uint_as_float(v.y & 0xffff0000u);
                    a0x += w0 * h0x; a1x += w1 * h1x;
                    a0y += w0 * h0y; a1y += w1 * h1y;
                }
            }
        }
        den0 = gsum32(den0);
        den1 = gsum32(den1);
        ux = 0.5f * (__fdividef(a0x, den0 + 1e-16f) +
                     __fdividef(a1x, den1 + 1e-16f));
        uy = 0.5f * (__fdividef(a0y, den0 + 1e-16f) +
                     __fdividef(a1y, den1 + 1e-16f));
    }
    // ---- HypAct with analytic norm tracking (2 group reductions) ----
    float Su = gsum32(ux * ux + uy * uy);
    float nu = fmaxf(sqrtf(Su), 1e-15f);
    float the = ftanh(nu);                    // |e| after expmap0
    float iv = __fdividef(the, nu);
    float ex = iv * ux, ey = iv * uy;
    float nh = the;
    if (the > MAXN_F) {
        float sc = MAXN_F / the;
        ex *= sc; ey *= sc; nh = MAXN_F;
    }
    float g = __fdividef(fatanh(fminf(nh, 1.f - 1e-7f)), fmaxf(nh, 1e-15f));
    float htx = g * ex, hty = g * ey;
    htx = htx < 0.f ? 0.01f * htx : htx;       // leaky
    hty = hty < 0.f ? 0.01f * hty : hty;
    float St = gsum32(htx * htx + hty * hty);
    float nt = fmaxf(sqrtf(St), 1e-15f);
    float to = ftanh(nt);
    float ov = __fdividef(to, nt);
    float ox = ov * htx, oy = ov * hty;
    if (to > MAXN_F) { float sc = MAXN_F / to; ox *= sc; oy *= sc; }
    if (valid)
        reinterpret_cast<float2*>(out)[(size_t)t * 32 + l] = make_float2(ox, oy);
}

extern "C" void kernel_launch(void* const* d_in, const int* in_sizes, int n_in,
                              void* d_out, int out_size, void* d_ws, size_t ws_size,
                              hipStream_t stream) {
    const float* x    = (const float*)d_in[0];
    const int*   eidx = (const int*)d_in[1];
    const float* W    = (const float*)d_in[2];
    const float* bias = (const float*)d_in[3];
    const float* atti = (const float*)d_in[4];
    const float* attj = (const float*)d_in[5];
    float* out = (float*)d_out;

    const int n = in_sizes[0] / DD;  // 100000
    const int E = in_sizes[1] / 2;   // 600000
    const size_t nf = (size_t)n;

    unsigned* xtb = (unsigned*)d_ws;            // n*64 dwords (bf16 pairs)
    float* ai  = (float*)(xtb + nf * DH);       // 2n
    float* aj  = ai + 2 * nf;                   // 2n
    int* deg    = (int*)(aj + 2 * nf);          // n
    int* rowptr = deg + nf;                     // n+1
    int* cursor = rowptr + nf + 1;              // n
    int* bsum   = cursor + nf;                  // 256
    int* csrc   = bsum + 256;                   // E
    s8v* wbf    = (s8v*)(csrc + E + 16);        // 2048 chunks (32 KB)
    float* hbg  = (float*)(wbf + 2048);         // 128
    float* cst  = hbg + 128;                    // 5

    const int nb = (n + 1023) / 1024;  // scan chunks (<=256)
    const int ngemm = (n + BM - 1) / BM;
    const int npair = (n + 1) / 2;     // node pairs (2 per wave)

    wprep_k<<<64, 256, 0, stream>>>(W, bias, atti, attj, wbf, hbg, cst, deg, n);
    gemm_node_k<<<ngemm, NTHR_G, 0, stream>>>(x, wbf, hbg, cst, atti, attj,
                                              eidx, deg, xtb, ai, aj, n, E);
    scan1_k<<<nb, 256, 0, stream>>>(deg, bsum, n);
    scan23_k<<<nb, 256, 0, stream>>>(deg, bsum, rowptr, cursor, n, E, nb);
    scatter_k<<<(E + 255) / 256, 256, 0, stream>>>(eidx, cursor, csrc, E);
    agg_fused_k<<<(npair + 3) / 4, 256, 0, stream>>>(rowptr, csrc, ai, aj, xtb,
                                                     out, n);
}